// Round 9
// baseline (805.213 us; speedup 1.0000x reference)
//
#include <hip/hip_runtime.h>
#include <hip/hip_bf16.h>
#include <stdint.h>

#define E_EDGES 80000
#define N_NODES 10000
#define HD      64
#define DDIST   128
#define NCOEF   49
#define W3OUT   224   // M0(7) * C_SPH(32)
#define WROW    2401  // 49*49
#define NELEM   90
#define EPW     16    // edges per wave in the MLP layer kernels

// Compile-time destination LUT: rel (0..2400) -> row*8+slot, or -1 if the
// column rel%49 is not one of {0,2,6,12,20,30,42}.
struct Lut { short v[WROW]; };
static constexpr Lut make_lut() {
    Lut L{};
    for (int rel = 0; rel < WROW; ++rel) {
        const int row = rel / 49;
        const int col = rel - row * 49;
        int slot = -1;
        const int cols[7] = {0, 2, 6, 12, 20, 30, 42};
        for (int s = 0; s < 7; ++s) if (cols[s] == col) slot = s;
        L.v[rel] = (slot >= 0) ? (short)(row * 8 + slot) : (short)-1;
    }
    return L;
}
__device__ const Lut d_lut = make_lut();

struct F8 { float v[8]; };

// ---------------------------------------------------------------------------
// k_pre: fold embedding tables through W1 slices; also zero cnt[].
// ---------------------------------------------------------------------------
__global__ __launch_bounds__(64) void k_pre(
    const float* __restrict__ semb, const float* __restrict__ temb,
    const float* __restrict__ W1,
    float* __restrict__ sW1, float* __restrict__ tW1, int* __restrict__ cnt)
{
    const int lane = threadIdx.x;
    const int zi = blockIdx.x * 64 + lane;
    if (zi < N_NODES) cnt[zi] = 0;
    const int z = blockIdx.x;
    if (z < NELEM) {
        float sa = 0.f, ta = 0.f;
        #pragma unroll 4
        for (int k = 0; k < HD; k++) {
            sa = fmaf(semb[z * HD + k], W1[(128 + k) * HD + lane], sa);
            ta = fmaf(temb[z * HD + k], W1[(192 + k) * HD + lane], ta);
        }
        sW1[z * HD + lane] = sa;
        tW1[z * HD + lane] = ta;
    }
}

// ---------------------------------------------------------------------------
// MLP layer kernels (round 9): lane = output channel; the wave's W-column
// lives in VGPRs (hoisted once); x is read at wave-uniform addresses
// (scalar path).  Inner loop = pure FMA, zero LDS, zero VGPR loads.
// ---------------------------------------------------------------------------
__device__ __forceinline__ float ln_silu(float acc, float bb, float gg, float be)
{
    float s = acc + bb;
    float sum = s, sum2 = s * s;
    #pragma unroll
    for (int off = 32; off > 0; off >>= 1) {
        sum  += __shfl_xor(sum,  off, 64);
        sum2 += __shfl_xor(sum2, off, 64);
    }
    const float mu  = sum * (1.f / 64.f);
    const float var = fmaxf(sum2 * (1.f / 64.f) - mu * mu, 0.f);
    const float t   = (s - mu) * rsqrtf(var + 1e-5f) * gg + be;
    return t / (1.f + expf(-t));
}

__global__ __launch_bounds__(256, 3) void k_l1(
    const int* __restrict__ an, const int* __restrict__ ei,
    const float* __restrict__ ed,
    const float* __restrict__ sW1, const float* __restrict__ tW1,
    const float* __restrict__ W1, const float* __restrict__ b1,
    const float* __restrict__ g1, const float* __restrict__ be1,
    float* __restrict__ h)
{
    const int wave = threadIdx.x >> 6;
    const int lane = threadIdx.x & 63;
    const int e0   = (blockIdx.x * 4 + wave) * EPW;

    float w1c[128];
    #pragma unroll
    for (int k = 0; k < 128; k++) w1c[k] = W1[k * HD + lane];
    const float bb = b1[lane], gg = g1[lane], be = be1[lane];

    for (int e = e0; e < e0 + EPW; e++) {
        const int zs = an[ei[e]];
        const int zt = an[ei[E_EDGES + e]];
        float acc = sW1[zs * HD + lane] + tW1[zt * HD + lane];
        #pragma unroll
        for (int kc = 0; kc < 16; kc++) {
            const F8 x = *(const F8*)(ed + (size_t)e * DDIST + kc * 8);
            #pragma unroll
            for (int j = 0; j < 8; j++)
                acc = fmaf(x.v[j], w1c[kc * 8 + j], acc);
        }
        h[(size_t)e * HD + lane] = ln_silu(acc, bb, gg, be);
    }
}

__global__ __launch_bounds__(256, 4) void k_l2(
    const float* __restrict__ h,
    const float* __restrict__ W2, const float* __restrict__ b2,
    const float* __restrict__ g2, const float* __restrict__ be2,
    float* __restrict__ h2)
{
    const int wave = threadIdx.x >> 6;
    const int lane = threadIdx.x & 63;
    const int e0   = (blockIdx.x * 4 + wave) * EPW;

    float w2c[64];
    #pragma unroll
    for (int k = 0; k < 64; k++) w2c[k] = W2[k * HD + lane];
    const float bb = b2[lane], gg = g2[lane], be = be2[lane];

    for (int e = e0; e < e0 + EPW; e++) {
        float acc = 0.f;
        #pragma unroll
        for (int kc = 0; kc < 8; kc++) {
            const F8 x = *(const F8*)(h + (size_t)e * HD + kc * 8);
            #pragma unroll
            for (int j = 0; j < 8; j++)
                acc = fmaf(x.v[j], w2c[kc * 8 + j], acc);
        }
        h2[(size_t)e * HD + lane] = ln_silu(acc, bb, gg, be);
    }
}

// gridDim.y = 2 passes; pass p: lane owns channels p*128+lane and p*128+64+lane.
__global__ __launch_bounds__(256, 3) void k_l3(
    const float* __restrict__ h2,
    const float* __restrict__ W3, const float* __restrict__ b3,
    float* __restrict__ y3)
{
    const int wave = threadIdx.x >> 6;
    const int lane = threadIdx.x & 63;
    const int e0   = (blockIdx.x * 4 + wave) * EPW;
    const int ch0  = blockIdx.y * 128 + lane;
    const int ch1  = ch0 + 64;
    const bool v1  = (ch1 < W3OUT);   // pass 1, lane>=32 has no second channel

    float w30[64], w31[64];
    #pragma unroll
    for (int k = 0; k < 64; k++) {
        w30[k] = W3[k * W3OUT + ch0];
        w31[k] = v1 ? W3[k * W3OUT + ch1] : 0.f;
    }
    const float b30 = b3[ch0];
    const float b31 = v1 ? b3[ch1] : 0.f;

    for (int e = e0; e < e0 + EPW; e++) {
        float a0 = 0.f, a1 = 0.f;
        #pragma unroll
        for (int kc = 0; kc < 8; kc++) {
            const F8 x = *(const F8*)(h2 + (size_t)e * HD + kc * 8);
            #pragma unroll
            for (int j = 0; j < 8; j++) {
                a0 = fmaf(x.v[j], w30[kc * 8 + j], a0);
                a1 = fmaf(x.v[j], w31[kc * 8 + j], a1);
            }
        }
        y3[(size_t)e * W3OUT + ch0] = (a0 + b30) * (1.0f / 5.862f);
        if (v1)
            y3[(size_t)e * W3OUT + ch1] = (a1 + b31) * (1.0f / 5.862f);
    }
}

// ---------------------------------------------------------------------------
// CSR build (frozen)
// ---------------------------------------------------------------------------
__global__ void k_count(const int* __restrict__ ei, int* __restrict__ cnt) {
    const int e = blockIdx.x * 256 + threadIdx.x;
    if (e < E_EDGES) atomicAdd(&cnt[ei[E_EDGES + e]], 1);
}

__global__ __launch_bounds__(1024) void k_scan(const int* __restrict__ cnt,
                                               int* __restrict__ offs,
                                               int* __restrict__ cursor) {
    __shared__ int wsum[16];
    __shared__ int carry_s;
    const int tid  = threadIdx.x;
    const int lane = tid & 63;
    const int wid  = tid >> 6;
    if (tid == 0) carry_s = 0;
    __syncthreads();
    for (int base = 0; base < N_NODES; base += 1024) {
        const int idx = base + tid;
        const int v = (idx < N_NODES) ? cnt[idx] : 0;
        int s = v;
        #pragma unroll
        for (int off = 1; off < 64; off <<= 1) {
            const int t = __shfl_up(s, off, 64);
            if (lane >= off) s += t;
        }
        if (lane == 63) wsum[wid] = s;
        __syncthreads();
        if (wid == 0) {
            const int t = (lane < 16) ? wsum[lane] : 0;
            int ss = t;
            #pragma unroll
            for (int off = 1; off < 16; off <<= 1) {
                const int u = __shfl_up(ss, off, 64);
                if (lane >= off) ss += u;
            }
            if (lane < 16) wsum[lane] = ss - t;
        }
        __syncthreads();
        const int carry = carry_s;
        const int excl = carry + wsum[wid] + s - v;
        if (idx < N_NODES) { offs[idx] = excl; cursor[idx] = excl; }
        __syncthreads();
        if (tid == 1023) carry_s = carry + wsum[15] + s;
    }
    __syncthreads();
    if (tid == 0) offs[N_NODES] = carry_s;
}

__global__ void k_scatter(const int* __restrict__ ei, int* __restrict__ cursor,
                          int* __restrict__ eids) {
    const int e = blockIdx.x * 256 + threadIdx.x;
    if (e < E_EDGES) {
        const int pos = atomicAdd(&cursor[ei[E_EDGES + e]], 1);
        eids[pos] = e;
    }
}

// ---------------------------------------------------------------------------
// Kernel B (FROZEN from round 6): block per node, coalesced float4 wigner
// stream, LDS LUT commit, depth-1 software pipeline.
// ---------------------------------------------------------------------------
__global__ __launch_bounds__(256) void k_out(
    const float* __restrict__ wig, const float* __restrict__ y3,
    const int* __restrict__ offs, const int* __restrict__ eids,
    float* __restrict__ out)
{
    __shared__ __align__(16) float wl[NCOEF * 8];
    __shared__ __align__(16) float yl[W3OUT];
    __shared__ short lut_s[WROW + 1];
    const int n   = blockIdx.x;
    const int tid = threadIdx.x;
    const int c   = tid & 31;
    const int rr  = tid >> 5;
    const int beg = offs[n];
    const int end = offs[n + 1];

    {
        const int* __restrict__ lsrc = (const int*)d_lut.v;
        int* __restrict__ ldst = (int*)lut_s;
        for (int j = tid; j < 1200; j += 256) ldst[j] = lsrc[j];
        if (tid == 0) lut_s[2400] = d_lut.v[2400];
    }

    float acc[7];
    #pragma unroll
    for (int r = 0; r < 7; r++) acc[r] = 0.f;

    const float4* __restrict__ wig4 = (const float4*)wig;
    const size_t NF4_TOTAL = ((size_t)E_EDGES * WROW) >> 2;

    float4 v0, v1, v2, yv;
    int d = 0;

    #define KOUT_ISSUE(E) do {                                              \
        const size_t rs = (size_t)(E) * WROW;                               \
        const size_t B  = rs >> 2;                                          \
        d = (int)(rs & 3);                                                  \
        v0 = make_float4(0.f,0.f,0.f,0.f); v1 = v0; v2 = v0;                \
        const size_t j0 = B + tid, j1 = j0 + 256, j2 = j0 + 512;            \
        if (j0 < NF4_TOTAL)               v0 = wig4[j0];                    \
        if (j1 < NF4_TOTAL)               v1 = wig4[j1];                    \
        if (tid < 89 && j2 < NF4_TOTAL)   v2 = wig4[j2];                    \
        if (tid < 56) yv = ((const float4*)(y3 + (size_t)(E) * W3OUT))[tid];\
    } while (0)

    #define KOUT_UNPACK(VV, R) do {                                         \
        const float xx[4] = {(VV).x, (VV).y, (VV).z, (VV).w};               \
        _Pragma("unroll")                                                   \
        for (int k = 0; k < 4; k++) {                                       \
            const int rel = 1024 * (R) + 4 * tid + k - d;                   \
            if (rel >= 0 && rel < WROW) {                                   \
                const int idx = lut_s[rel];                                 \
                if (idx >= 0) wl[idx] = xx[k];                              \
            }                                                               \
        }                                                                   \
    } while (0)

    #define KOUT_COMMIT() do {                                              \
        KOUT_UNPACK(v0, 0); KOUT_UNPACK(v1, 1); KOUT_UNPACK(v2, 2);         \
        if (tid < 56) ((float4*)yl)[tid] = yv;                              \
    } while (0)

    if (beg < end) {
        KOUT_ISSUE(eids[beg]);
        __syncthreads();               // LUT staged
        KOUT_COMMIT();
    }

    for (int ie = beg; ie < end; ie++) {
        __syncthreads();
        if (ie + 1 < end) {
            const int e2 = eids[ie + 1];
            KOUT_ISSUE(e2);
        }
        float yr[7];
        #pragma unroll
        for (int l = 0; l < 7; l++) yr[l] = yl[l * 32 + c];
        #pragma unroll
        for (int r = 0; r < 7; r++) {
            const int i = r * 8 + rr;
            if (i < NCOEF) {
                const float4 wa = *(const float4*)(wl + i * 8);
                const float4 wb = *(const float4*)(wl + i * 8 + 4);
                acc[r] += wa.x * yr[0] + wa.y * yr[1] + wa.z * yr[2] + wa.w * yr[3]
                        + wb.x * yr[4] + wb.y * yr[5] + wb.z * yr[6];
            }
        }
        __syncthreads();
        if (ie + 1 < end)
            KOUT_COMMIT();
    }

    #pragma unroll
    for (int r = 0; r < 7; r++) {
        const int i = r * 8 + rr;
        if (i < NCOEF) out[(size_t)n * (NCOEF * 32) + i * 32 + c] = acc[r];
    }
}

// ---------------------------------------------------------------------------
extern "C" void kernel_launch(void* const* d_in, const int* in_sizes, int n_in,
                              void* d_out, int out_size, void* d_ws, size_t ws_size,
                              hipStream_t stream)
{
    const int*   an   = (const int*)  d_in[0];
    const int*   ei   = (const int*)  d_in[1];
    const float* ed   = (const float*)d_in[2];
    const float* wig  = (const float*)d_in[3];
    const float* semb = (const float*)d_in[4];
    const float* temb = (const float*)d_in[5];
    const float* W1   = (const float*)d_in[6];
    const float* b1   = (const float*)d_in[7];
    const float* g1   = (const float*)d_in[8];
    const float* be1  = (const float*)d_in[9];
    const float* W2   = (const float*)d_in[10];
    const float* b2   = (const float*)d_in[11];
    const float* g2   = (const float*)d_in[12];
    const float* be2  = (const float*)d_in[13];
    const float* W3   = (const float*)d_in[14];
    const float* b3   = (const float*)d_in[15];
    float* out = (float*)d_out;

    char* ws = (char*)d_ws;
    const size_t y3_bytes = (size_t)E_EDGES * W3OUT * sizeof(float); // 71.68 MB
    const size_t h_bytes  = (size_t)E_EDGES * HD * sizeof(float);    // 20.48 MB
    float* y3     = (float*)ws;
    float* hbuf   = (float*)(ws + y3_bytes);
    float* h2buf  = (float*)(ws + y3_bytes + h_bytes);
    int*   cnt    = (int*)(ws + y3_bytes + 2 * h_bytes);
    int*   offs   = cnt + N_NODES;
    int*   cursor = offs + N_NODES + 1;
    int*   eids   = cursor + N_NODES;
    float* sW1    = (float*)(eids + E_EDGES);
    float* tW1    = sW1 + NELEM * HD;
    const size_t need = y3_bytes + 2 * h_bytes +
        sizeof(int) * ((size_t)N_NODES + (N_NODES + 1) + N_NODES + E_EDGES) +
        sizeof(float) * (2 * NELEM * HD);
    if (ws_size < need) return;

    const int mlp_blocks = E_EDGES / (4 * EPW);   // 1250

    k_pre<<<(N_NODES + 63) / 64, 64, 0, stream>>>(semb, temb, W1, sW1, tW1, cnt);
    k_l1<<<mlp_blocks, 256, 0, stream>>>(an, ei, ed, sW1, tW1,
                                         W1, b1, g1, be1, hbuf);
    k_l2<<<mlp_blocks, 256, 0, stream>>>(hbuf, W2, b2, g2, be2, h2buf);
    k_l3<<<dim3(mlp_blocks, 2), 256, 0, stream>>>(h2buf, W3, b3, y3);
    k_count<<<(E_EDGES + 255) / 256, 256, 0, stream>>>(ei, cnt);
    k_scan<<<1, 1024, 0, stream>>>(cnt, offs, cursor);
    k_scatter<<<(E_EDGES + 255) / 256, 256, 0, stream>>>(ei, cursor, eids);
    k_out<<<N_NODES, 256, 0, stream>>>(wig, y3, offs, eids, out);
}

// Round 10
// 477.497 us; speedup vs baseline: 1.6863x; 1.6863x over previous
//
#include <hip/hip_runtime.h>
#include <hip/hip_bf16.h>
#include <stdint.h>

#define E_EDGES 80000
#define N_NODES 10000
#define HD      64
#define DDIST   128
#define NCOEF   49
#define W3OUT   224   // M0(7) * C_SPH(32)
#define WROW    2401  // 49*49
#define NELEM   90

// Compile-time destination LUT: rel (0..2400) -> row*8+slot, or -1 if the
// column rel%49 is not one of {0,2,6,12,20,30,42}.
struct Lut { short v[WROW]; };
static constexpr Lut make_lut() {
    Lut L{};
    for (int rel = 0; rel < WROW; ++rel) {
        const int row = rel / 49;
        const int col = rel - row * 49;
        int slot = -1;
        const int cols[7] = {0, 2, 6, 12, 20, 30, 42};
        for (int s = 0; s < 7; ++s) if (cols[s] == col) slot = s;
        L.v[rel] = (slot >= 0) ? (short)(row * 8 + slot) : (short)-1;
    }
    return L;
}
__device__ const Lut d_lut = make_lut();

// ---------------------------------------------------------------------------
// k_pre: fold embedding tables through W1 slices, stored TRANSPOSED
// (sW1T[n][z]) so the per-edge gather in k_mlp_lane touches a 360B window.
// Also zeroes cnt[].
// ---------------------------------------------------------------------------
__global__ __launch_bounds__(64) void k_pre(
    const float* __restrict__ semb, const float* __restrict__ temb,
    const float* __restrict__ W1,
    float* __restrict__ sW1T, float* __restrict__ tW1T, int* __restrict__ cnt)
{
    const int lane = threadIdx.x;
    const int zi = blockIdx.x * 64 + lane;
    if (zi < N_NODES) cnt[zi] = 0;
    const int z = blockIdx.x;
    if (z < NELEM) {
        float sa = 0.f, ta = 0.f;
        #pragma unroll 4
        for (int k = 0; k < HD; k++) {
            sa = fmaf(semb[z * HD + k], W1[(128 + k) * HD + lane], sa);
            ta = fmaf(temb[z * HD + k], W1[(192 + k) * HD + lane], ta);
        }
        sW1T[lane * NELEM + z] = sa;
        tW1T[lane * NELEM + z] = ta;
    }
}

// ---------------------------------------------------------------------------
// k_tr: tile-transpose edge_distance [80000][128] -> edT [128][80000].
// ---------------------------------------------------------------------------
__global__ __launch_bounds__(256) void k_tr(const float* __restrict__ ed,
                                            float* __restrict__ edT)
{
    __shared__ float tile[64][65];
    const int e0 = blockIdx.x * 64;
    const int k0 = blockIdx.y * 64;
    const int tx = threadIdx.x & 63;
    const int ty = threadIdx.x >> 6;    // 0..3
    #pragma unroll
    for (int i = 0; i < 16; i++) {
        const int r = i * 4 + ty;
        tile[r][tx] = ed[(size_t)(e0 + r) * DDIST + k0 + tx];
    }
    __syncthreads();
    #pragma unroll
    for (int i = 0; i < 16; i++) {
        const int r = i * 4 + ty;       // k-row within tile
        edT[(size_t)(k0 + r) * E_EDGES + e0 + tx] = tile[tx][r];
    }
}

// ---------------------------------------------------------------------------
// k_mlp_lane (round 10): one wave per 64 edges, LANE = EDGE.
// All channels of the lane's edge live in registers (static indexing only);
// weights are wave-uniform -> scalar loads; x loads coalesced via edT;
// LayerNorm is lane-local; h/h2 never leave registers; y3 stored through a
// small LDS transpose for coalescing.  No spills: peak ~140 VGPR.
// ---------------------------------------------------------------------------
__global__ __launch_bounds__(64, 2) void k_mlp_lane(
    const int* __restrict__ an, const int* __restrict__ ei,
    const float* __restrict__ edT,
    const float* __restrict__ sW1T, const float* __restrict__ tW1T,
    const float* __restrict__ W1, const float* __restrict__ b1,
    const float* __restrict__ g1, const float* __restrict__ be1,
    const float* __restrict__ W2, const float* __restrict__ b2,
    const float* __restrict__ g2, const float* __restrict__ be2,
    const float* __restrict__ W3, const float* __restrict__ b3,
    float* __restrict__ y3)
{
    __shared__ float buf[64][33];
    const int lane = threadIdx.x;
    const int e0   = blockIdx.x * 64;
    const int e    = e0 + lane;

    // ---- layer 1: init from transposed fold tables --------------------------
    const int zs = an[ei[e]];
    const int zt = an[ei[E_EDGES + e]];
    float acc[64];
    #pragma unroll
    for (int n = 0; n < 64; n++)
        acc[n] = sW1T[n * NELEM + zs] + tW1T[n * NELEM + zt];

    // ---- layer 1: ed part, coalesced x, scalar weights ----------------------
    #pragma unroll 8
    for (int k = 0; k < 128; k++) {
        const float xk = edT[(size_t)k * E_EDGES + e];
        #pragma unroll
        for (int n = 0; n < 64; n++)
            acc[n] = fmaf(W1[k * HD + n], xk, acc[n]);
    }

    // ---- LN + silu (1), lane-local ------------------------------------------
    float h[64];
    {
        #pragma unroll
        for (int n = 0; n < 64; n++) acc[n] += b1[n];
        float p0 = 0.f, p1 = 0.f, p2 = 0.f, p3 = 0.f;
        float q0 = 0.f, q1 = 0.f, q2 = 0.f, q3 = 0.f;
        #pragma unroll
        for (int n = 0; n < 64; n += 4) {
            p0 += acc[n];     q0 = fmaf(acc[n],     acc[n],     q0);
            p1 += acc[n + 1]; q1 = fmaf(acc[n + 1], acc[n + 1], q1);
            p2 += acc[n + 2]; q2 = fmaf(acc[n + 2], acc[n + 2], q2);
            p3 += acc[n + 3]; q3 = fmaf(acc[n + 3], acc[n + 3], q3);
        }
        const float mu  = (p0 + p1 + p2 + p3) * (1.f / 64.f);
        const float var = fmaxf((q0 + q1 + q2 + q3) * (1.f / 64.f) - mu * mu, 0.f);
        const float rstd = rsqrtf(var + 1e-5f);
        #pragma unroll
        for (int n = 0; n < 64; n++) {
            const float t = (acc[n] - mu) * rstd * g1[n] + be1[n];
            h[n] = t / (1.f + expf(-t));
        }
    }

    // ---- layer 2 -------------------------------------------------------------
    float a2[64];
    #pragma unroll
    for (int n = 0; n < 64; n++) a2[n] = b2[n];
    #pragma unroll
    for (int k = 0; k < 64; k++) {
        const float xk = h[k];
        #pragma unroll
        for (int n = 0; n < 64; n++)
            a2[n] = fmaf(W2[k * HD + n], xk, a2[n]);
    }

    // ---- LN + silu (2) --------------------------------------------------------
    float h2[64];
    {
        float p0 = 0.f, p1 = 0.f, p2 = 0.f, p3 = 0.f;
        float q0 = 0.f, q1 = 0.f, q2 = 0.f, q3 = 0.f;
        #pragma unroll
        for (int n = 0; n < 64; n += 4) {
            p0 += a2[n];     q0 = fmaf(a2[n],     a2[n],     q0);
            p1 += a2[n + 1]; q1 = fmaf(a2[n + 1], a2[n + 1], q1);
            p2 += a2[n + 2]; q2 = fmaf(a2[n + 2], a2[n + 2], q2);
            p3 += a2[n + 3]; q3 = fmaf(a2[n + 3], a2[n + 3], q3);
        }
        const float mu  = (p0 + p1 + p2 + p3) * (1.f / 64.f);
        const float var = fmaxf((q0 + q1 + q2 + q3) * (1.f / 64.f) - mu * mu, 0.f);
        const float rstd = rsqrtf(var + 1e-5f);
        #pragma unroll
        for (int n = 0; n < 64; n++) {
            const float t = (a2[n] - mu) * rstd * g2[n] + be2[n];
            h2[n] = t / (1.f + expf(-t));
        }
    }

    // ---- layer 3: 7 chunks of 32 channels; LDS-transposed coalesced store ----
    for (int chunk = 0; chunk < 7; chunk++) {
        float a3[32];
        #pragma unroll
        for (int c = 0; c < 32; c++) a3[c] = b3[chunk * 32 + c];
        #pragma unroll
        for (int k = 0; k < 64; k++) {
            const float xk = h2[k];
            #pragma unroll
            for (int c = 0; c < 32; c++)
                a3[c] = fmaf(W3[k * W3OUT + chunk * 32 + c], xk, a3[c]);
        }
        __syncthreads();   // previous chunk's readers done with buf
        #pragma unroll
        for (int c = 0; c < 32; c++)
            buf[lane][c] = a3[c] * (1.0f / 5.862f);
        __syncthreads();   // buf visible
        #pragma unroll
        for (int j = 0; j < 32; j++) {
            const int eoff = j * 2 + (lane >> 5);
            const int c    = lane & 31;
            y3[(size_t)(e0 + eoff) * W3OUT + chunk * 32 + c] = buf[eoff][c];
        }
    }
}

// ---------------------------------------------------------------------------
// CSR build (frozen)
// ---------------------------------------------------------------------------
__global__ void k_count(const int* __restrict__ ei, int* __restrict__ cnt) {
    const int e = blockIdx.x * 256 + threadIdx.x;
    if (e < E_EDGES) atomicAdd(&cnt[ei[E_EDGES + e]], 1);
}

__global__ __launch_bounds__(1024) void k_scan(const int* __restrict__ cnt,
                                               int* __restrict__ offs,
                                               int* __restrict__ cursor) {
    __shared__ int wsum[16];
    __shared__ int carry_s;
    const int tid  = threadIdx.x;
    const int lane = tid & 63;
    const int wid  = tid >> 6;
    if (tid == 0) carry_s = 0;
    __syncthreads();
    for (int base = 0; base < N_NODES; base += 1024) {
        const int idx = base + tid;
        const int v = (idx < N_NODES) ? cnt[idx] : 0;
        int s = v;
        #pragma unroll
        for (int off = 1; off < 64; off <<= 1) {
            const int t = __shfl_up(s, off, 64);
            if (lane >= off) s += t;
        }
        if (lane == 63) wsum[wid] = s;
        __syncthreads();
        if (wid == 0) {
            const int t = (lane < 16) ? wsum[lane] : 0;
            int ss = t;
            #pragma unroll
            for (int off = 1; off < 16; off <<= 1) {
                const int u = __shfl_up(ss, off, 64);
                if (lane >= off) ss += u;
            }
            if (lane < 16) wsum[lane] = ss - t;
        }
        __syncthreads();
        const int carry = carry_s;
        const int excl = carry + wsum[wid] + s - v;
        if (idx < N_NODES) { offs[idx] = excl; cursor[idx] = excl; }
        __syncthreads();
        if (tid == 1023) carry_s = carry + wsum[15] + s;
    }
    __syncthreads();
    if (tid == 0) offs[N_NODES] = carry_s;
}

__global__ void k_scatter(const int* __restrict__ ei, int* __restrict__ cursor,
                          int* __restrict__ eids) {
    const int e = blockIdx.x * 256 + threadIdx.x;
    if (e < E_EDGES) {
        const int pos = atomicAdd(&cursor[ei[E_EDGES + e]], 1);
        eids[pos] = e;
    }
}

// ---------------------------------------------------------------------------
// Kernel B (FROZEN from round 6): block per node, coalesced float4 wigner
// stream, LDS LUT commit, depth-1 software pipeline.
// ---------------------------------------------------------------------------
__global__ __launch_bounds__(256) void k_out(
    const float* __restrict__ wig, const float* __restrict__ y3,
    const int* __restrict__ offs, const int* __restrict__ eids,
    float* __restrict__ out)
{
    __shared__ __align__(16) float wl[NCOEF * 8];
    __shared__ __align__(16) float yl[W3OUT];
    __shared__ short lut_s[WROW + 1];
    const int n   = blockIdx.x;
    const int tid = threadIdx.x;
    const int c   = tid & 31;
    const int rr  = tid >> 5;
    const int beg = offs[n];
    const int end = offs[n + 1];

    {
        const int* __restrict__ lsrc = (const int*)d_lut.v;
        int* __restrict__ ldst = (int*)lut_s;
        for (int j = tid; j < 1200; j += 256) ldst[j] = lsrc[j];
        if (tid == 0) lut_s[2400] = d_lut.v[2400];
    }

    float acc[7];
    #pragma unroll
    for (int r = 0; r < 7; r++) acc[r] = 0.f;

    const float4* __restrict__ wig4 = (const float4*)wig;
    const size_t NF4_TOTAL = ((size_t)E_EDGES * WROW) >> 2;

    float4 v0, v1, v2, yv;
    int d = 0;

    #define KOUT_ISSUE(E) do {                                              \
        const size_t rs = (size_t)(E) * WROW;                               \
        const size_t B  = rs >> 2;                                          \
        d = (int)(rs & 3);                                                  \
        v0 = make_float4(0.f,0.f,0.f,0.f); v1 = v0; v2 = v0;                \
        const size_t j0 = B + tid, j1 = j0 + 256, j2 = j0 + 512;            \
        if (j0 < NF4_TOTAL)               v0 = wig4[j0];                    \
        if (j1 < NF4_TOTAL)               v1 = wig4[j1];                    \
        if (tid < 89 && j2 < NF4_TOTAL)   v2 = wig4[j2];                    \
        if (tid < 56) yv = ((const float4*)(y3 + (size_t)(E) * W3OUT))[tid];\
    } while (0)

    #define KOUT_UNPACK(VV, R) do {                                         \
        const float xx[4] = {(VV).x, (VV).y, (VV).z, (VV).w};               \
        _Pragma("unroll")                                                   \
        for (int k = 0; k < 4; k++) {                                       \
            const int rel = 1024 * (R) + 4 * tid + k - d;                   \
            if (rel >= 0 && rel < WROW) {                                   \
                const int idx = lut_s[rel];                                 \
                if (idx >= 0) wl[idx] = xx[k];                              \
            }                                                               \
        }                                                                   \
    } while (0)

    #define KOUT_COMMIT() do {                                              \
        KOUT_UNPACK(v0, 0); KOUT_UNPACK(v1, 1); KOUT_UNPACK(v2, 2);         \
        if (tid < 56) ((float4*)yl)[tid] = yv;                              \
    } while (0)

    if (beg < end) {
        KOUT_ISSUE(eids[beg]);
        __syncthreads();               // LUT staged
        KOUT_COMMIT();
    }

    for (int ie = beg; ie < end; ie++) {
        __syncthreads();
        if (ie + 1 < end) {
            const int e2 = eids[ie + 1];
            KOUT_ISSUE(e2);
        }
        float yr[7];
        #pragma unroll
        for (int l = 0; l < 7; l++) yr[l] = yl[l * 32 + c];
        #pragma unroll
        for (int r = 0; r < 7; r++) {
            const int i = r * 8 + rr;
            if (i < NCOEF) {
                const float4 wa = *(const float4*)(wl + i * 8);
                const float4 wb = *(const float4*)(wl + i * 8 + 4);
                acc[r] += wa.x * yr[0] + wa.y * yr[1] + wa.z * yr[2] + wa.w * yr[3]
                        + wb.x * yr[4] + wb.y * yr[5] + wb.z * yr[6];
            }
        }
        __syncthreads();
        if (ie + 1 < end)
            KOUT_COMMIT();
    }

    #pragma unroll
    for (int r = 0; r < 7; r++) {
        const int i = r * 8 + rr;
        if (i < NCOEF) out[(size_t)n * (NCOEF * 32) + i * 32 + c] = acc[r];
    }
}

// ---------------------------------------------------------------------------
extern "C" void kernel_launch(void* const* d_in, const int* in_sizes, int n_in,
                              void* d_out, int out_size, void* d_ws, size_t ws_size,
                              hipStream_t stream)
{
    const int*   an   = (const int*)  d_in[0];
    const int*   ei   = (const int*)  d_in[1];
    const float* ed   = (const float*)d_in[2];
    const float* wig  = (const float*)d_in[3];
    const float* semb = (const float*)d_in[4];
    const float* temb = (const float*)d_in[5];
    const float* W1   = (const float*)d_in[6];
    const float* b1   = (const float*)d_in[7];
    const float* g1   = (const float*)d_in[8];
    const float* be1  = (const float*)d_in[9];
    const float* W2   = (const float*)d_in[10];
    const float* b2   = (const float*)d_in[11];
    const float* g2   = (const float*)d_in[12];
    const float* be2  = (const float*)d_in[13];
    const float* W3   = (const float*)d_in[14];
    const float* b3   = (const float*)d_in[15];
    float* out = (float*)d_out;

    char* ws = (char*)d_ws;
    const size_t y3_bytes  = (size_t)E_EDGES * W3OUT * sizeof(float); // 71.68 MB
    const size_t edT_bytes = (size_t)E_EDGES * DDIST * sizeof(float); // 40.96 MB
    float* y3     = (float*)ws;
    float* edT    = (float*)(ws + y3_bytes);
    int*   cnt    = (int*)(ws + y3_bytes + edT_bytes);
    int*   offs   = cnt + N_NODES;
    int*   cursor = offs + N_NODES + 1;
    int*   eids   = cursor + N_NODES;
    float* sW1T   = (float*)(eids + E_EDGES);
    float* tW1T   = sW1T + NELEM * HD;
    const size_t need = y3_bytes + edT_bytes +
        sizeof(int) * ((size_t)N_NODES + (N_NODES + 1) + N_NODES + E_EDGES) +
        sizeof(float) * (2 * NELEM * HD);
    if (ws_size < need) return;

    k_pre<<<(N_NODES + 63) / 64, 64, 0, stream>>>(semb, temb, W1, sW1T, tW1T, cnt);
    k_tr<<<dim3(E_EDGES / 64, DDIST / 64), 256, 0, stream>>>(ed, edT);
    k_mlp_lane<<<E_EDGES / 64, 64, 0, stream>>>(an, ei, edT, sW1T, tW1T,
                                                W1, b1, g1, be1,
                                                W2, b2, g2, be2, W3, b3, y3);
    k_count<<<(E_EDGES + 255) / 256, 256, 0, stream>>>(ei, cnt);
    k_scan<<<1, 1024, 0, stream>>>(cnt, offs, cursor);
    k_scatter<<<(E_EDGES + 255) / 256, 256, 0, stream>>>(ei, cursor, eids);
    k_out<<<N_NODES, 256, 0, stream>>>(wig, y3, offs, eids, out);
}

// Round 11
// 351.990 us; speedup vs baseline: 2.2876x; 1.3566x over previous
//
#include <hip/hip_runtime.h>
#include <hip/hip_bf16.h>
#include <stdint.h>

#define E_EDGES 80000
#define N_NODES 10000
#define HD      64
#define DDIST   128
#define NCOEF   49
#define W3OUT   224   // M0(7) * C_SPH(32)
#define WROW    2401  // 49*49
#define NELEM   90

struct F8 { float v[8]; };

// ---------------------------------------------------------------------------
// k_pre (r7 verbatim): fold embedding tables through W1 slices.
// ---------------------------------------------------------------------------
__global__ __launch_bounds__(64) void k_pre(
    const float* __restrict__ semb, const float* __restrict__ temb,
    const float* __restrict__ W1,
    float* __restrict__ sW1, float* __restrict__ tW1)
{
    const int z    = blockIdx.x;
    const int lane = threadIdx.x;
    float sa = 0.f, ta = 0.f;
    #pragma unroll 4
    for (int k = 0; k < HD; k++) {
        sa = fmaf(semb[z * HD + k], W1[(128 + k) * HD + lane], sa);
        ta = fmaf(temb[z * HD + k], W1[(192 + k) * HD + lane], ta);
    }
    sW1[z * HD + lane] = sa;
    tW1[z * HD + lane] = ta;
}

// ---------------------------------------------------------------------------
// k_mlp (r7 verbatim, best measured MLP: 146 us): 4 edges/wave, 4 waves/blk,
// layer-1 K=128 via precomputed embedding fold; zeroes cnt[].
// ---------------------------------------------------------------------------
__global__ __launch_bounds__(256, 4) void k_mlp(
    const int* __restrict__ an, const int* __restrict__ ei,
    const float* __restrict__ ed,
    const float* __restrict__ sW1, const float* __restrict__ tW1,
    const float* __restrict__ W1, const float* __restrict__ b1,
    const float* __restrict__ g1, const float* __restrict__ be1,
    const float* __restrict__ W2, const float* __restrict__ b2,
    const float* __restrict__ g2, const float* __restrict__ be2,
    const float* __restrict__ W3, const float* __restrict__ b3,
    int* __restrict__ cnt, float* __restrict__ y3)
{
    __shared__ float hT[4][HD * 4];
    __shared__ float h2T[4][HD * 4];
    const int tid  = threadIdx.x;

    const int zi = blockIdx.x * 256 + tid;
    if (zi < N_NODES) cnt[zi] = 0;

    const int wave = tid >> 6;
    const int lane = tid & 63;
    const int e0u  = __builtin_amdgcn_readfirstlane(blockIdx.x * 16 + wave * 4);
    float* __restrict__ hw  = hT[wave];
    float* __restrict__ h2w = h2T[wave];

    float acc[4];
    #pragma unroll
    for (int ep = 0; ep < 4; ep++) {
        const int sn = ei[e0u + ep];
        const int tn = ei[E_EDGES + e0u + ep];
        acc[ep] = sW1[an[sn] * HD + lane] + tW1[an[tn] * HD + lane];
    }

    #pragma unroll 2
    for (int kc = 0; kc < 16; kc++) {
        float w[8];
        #pragma unroll
        for (int j = 0; j < 8; j++) w[j] = W1[(kc * 8 + j) * HD + lane];
        #pragma unroll
        for (int ep = 0; ep < 4; ep++) {
            const F8 x = *(const F8*)(ed + (size_t)(e0u + ep) * DDIST + kc * 8);
            acc[ep] = fmaf(w[0], x.v[0], acc[ep]);
            acc[ep] = fmaf(w[1], x.v[1], acc[ep]);
            acc[ep] = fmaf(w[2], x.v[2], acc[ep]);
            acc[ep] = fmaf(w[3], x.v[3], acc[ep]);
            acc[ep] = fmaf(w[4], x.v[4], acc[ep]);
            acc[ep] = fmaf(w[5], x.v[5], acc[ep]);
            acc[ep] = fmaf(w[6], x.v[6], acc[ep]);
            acc[ep] = fmaf(w[7], x.v[7], acc[ep]);
        }
    }

    {
        const float bb = b1[lane], gg = g1[lane], be = be1[lane];
        #pragma unroll
        for (int ep = 0; ep < 4; ep++) {
            float h = acc[ep] + bb;
            float s = h, s2 = h * h;
            #pragma unroll
            for (int off = 32; off > 0; off >>= 1) {
                s  += __shfl_xor(s,  off, 64);
                s2 += __shfl_xor(s2, off, 64);
            }
            const float mu  = s * (1.f / 64.f);
            const float var = fmaxf(s2 * (1.f / 64.f) - mu * mu, 0.f);
            const float t   = (h - mu) * rsqrtf(var + 1e-5f) * gg + be;
            hw[lane * 4 + ep] = t / (1.f + expf(-t));
        }
    }
    __syncthreads();

    #pragma unroll
    for (int ep = 0; ep < 4; ep++) acc[ep] = 0.f;
    #pragma unroll 4
    for (int k = 0; k < HD; k++) {
        const float w  = W2[k * HD + lane];
        const float4 xa = *(const float4*)(hw + k * 4);
        acc[0] = fmaf(w, xa.x, acc[0]); acc[1] = fmaf(w, xa.y, acc[1]);
        acc[2] = fmaf(w, xa.z, acc[2]); acc[3] = fmaf(w, xa.w, acc[3]);
    }
    {
        const float bb = b2[lane], gg = g2[lane], be = be2[lane];
        #pragma unroll
        for (int ep = 0; ep < 4; ep++) {
            float h = acc[ep] + bb;
            float s = h, s2 = h * h;
            #pragma unroll
            for (int off = 32; off > 0; off >>= 1) {
                s  += __shfl_xor(s,  off, 64);
                s2 += __shfl_xor(s2, off, 64);
            }
            const float mu  = s * (1.f / 64.f);
            const float var = fmaxf(s2 * (1.f / 64.f) - mu * mu, 0.f);
            const float t   = (h - mu) * rsqrtf(var + 1e-5f) * gg + be;
            h2w[lane * 4 + ep] = t / (1.f + expf(-t));
        }
    }
    __syncthreads();

    float a2[4][4];
    #pragma unroll
    for (int ch = 0; ch < 4; ch++)
        #pragma unroll
        for (int ep = 0; ep < 4; ep++) a2[ch][ep] = 0.f;

    #pragma unroll 2
    for (int k = 0; k < HD; k++) {
        const float w0 = W3[k * W3OUT + lane];
        const float w1 = W3[k * W3OUT + 64 + lane];
        const float w2 = W3[k * W3OUT + 128 + lane];
        const float w3 = (lane < 32) ? W3[k * W3OUT + 192 + lane] : 0.f;
        const float4 xa = *(const float4*)(h2w + k * 4);
        a2[0][0] = fmaf(w0, xa.x, a2[0][0]); a2[0][1] = fmaf(w0, xa.y, a2[0][1]);
        a2[0][2] = fmaf(w0, xa.z, a2[0][2]); a2[0][3] = fmaf(w0, xa.w, a2[0][3]);
        a2[1][0] = fmaf(w1, xa.x, a2[1][0]); a2[1][1] = fmaf(w1, xa.y, a2[1][1]);
        a2[1][2] = fmaf(w1, xa.z, a2[1][2]); a2[1][3] = fmaf(w1, xa.w, a2[1][3]);
        a2[2][0] = fmaf(w2, xa.x, a2[2][0]); a2[2][1] = fmaf(w2, xa.y, a2[2][1]);
        a2[2][2] = fmaf(w2, xa.z, a2[2][2]); a2[2][3] = fmaf(w2, xa.w, a2[2][3]);
        a2[3][0] = fmaf(w3, xa.x, a2[3][0]); a2[3][1] = fmaf(w3, xa.y, a2[3][1]);
        a2[3][2] = fmaf(w3, xa.z, a2[3][2]); a2[3][3] = fmaf(w3, xa.w, a2[3][3]);
    }

    #pragma unroll
    for (int ch = 0; ch < 4; ch++) {
        const int chn = ch * 64 + lane;
        if (ch < 3 || lane < 32) {
            const float bb3 = b3[chn];
            #pragma unroll
            for (int ep = 0; ep < 4; ep++)
                y3[(size_t)(e0u + ep) * W3OUT + chn] =
                    (a2[ch][ep] + bb3) * (1.0f / 5.862f);
        }
    }
}

// ---------------------------------------------------------------------------
// CSR build (frozen)
// ---------------------------------------------------------------------------
__global__ void k_count(const int* __restrict__ ei, int* __restrict__ cnt) {
    const int e = blockIdx.x * 256 + threadIdx.x;
    if (e < E_EDGES) atomicAdd(&cnt[ei[E_EDGES + e]], 1);
}

__global__ __launch_bounds__(1024) void k_scan(const int* __restrict__ cnt,
                                               int* __restrict__ offs,
                                               int* __restrict__ cursor) {
    __shared__ int wsum[16];
    __shared__ int carry_s;
    const int tid  = threadIdx.x;
    const int lane = tid & 63;
    const int wid  = tid >> 6;
    if (tid == 0) carry_s = 0;
    __syncthreads();
    for (int base = 0; base < N_NODES; base += 1024) {
        const int idx = base + tid;
        const int v = (idx < N_NODES) ? cnt[idx] : 0;
        int s = v;
        #pragma unroll
        for (int off = 1; off < 64; off <<= 1) {
            const int t = __shfl_up(s, off, 64);
            if (lane >= off) s += t;
        }
        if (lane == 63) wsum[wid] = s;
        __syncthreads();
        if (wid == 0) {
            const int t = (lane < 16) ? wsum[lane] : 0;
            int ss = t;
            #pragma unroll
            for (int off = 1; off < 16; off <<= 1) {
                const int u = __shfl_up(ss, off, 64);
                if (lane >= off) ss += u;
            }
            if (lane < 16) wsum[lane] = ss - t;
        }
        __syncthreads();
        const int carry = carry_s;
        const int excl = carry + wsum[wid] + s - v;
        if (idx < N_NODES) { offs[idx] = excl; cursor[idx] = excl; }
        __syncthreads();
        if (tid == 1023) carry_s = carry + wsum[15] + s;
    }
    __syncthreads();
    if (tid == 0) offs[N_NODES] = carry_s;
}

__global__ void k_scatter(const int* __restrict__ ei, int* __restrict__ cursor,
                          int* __restrict__ eids) {
    const int e = blockIdx.x * 256 + threadIdx.x;
    if (e < E_EDGES) {
        const int pos = atomicAdd(&cursor[ei[E_EDGES + e]], 1);
        eids[pos] = e;
    }
}

// ---------------------------------------------------------------------------
// k_out (round 11): ONE WAVE PER NODE, barrier-free.
// Each lane directly gathers 6 of the 343 needed wigner elements
// (t = lane+64g: row=t/7, l=t%7, col=l*l+l) into a wave-private,
// double-buffered LDS tile; compute c=lane&31, h=lane>>5, rows i=2r+h.
// Wave-internal ordering via s_waitcnt lgkmcnt(0) (no __syncthreads).
// ---------------------------------------------------------------------------
__global__ __launch_bounds__(256) void k_out(
    const float* __restrict__ wig, const float* __restrict__ y3,
    const int* __restrict__ offs, const int* __restrict__ eids,
    float* __restrict__ out)
{
    __shared__ __align__(16) float wl[4][2][400];   // [wave][buf][i*8+l]
    __shared__ __align__(16) float yl[4][2][224];   // [wave][buf][l*32+c]
    const int tid  = threadIdx.x;
    const int wave = tid >> 6;
    const int lane = tid & 63;
    const int n    = blockIdx.x * 4 + wave;
    const int c    = lane & 31;
    const int h    = lane >> 5;
    const int beg  = offs[n];
    const int end  = offs[n + 1];

    float acc[25];
    #pragma unroll
    for (int r = 0; r < 25; r++) acc[r] = 0.f;

    float gv[6];
    float4 yv;

    #define GATHER(E) do {                                                  \
        const float* __restrict__ wb_ = wig + (size_t)(E) * WROW;           \
        _Pragma("unroll")                                                   \
        for (int g = 0; g < 6; g++) {                                       \
            const int t = lane + 64 * g;                                    \
            if (t < 343) {                                                  \
                const int row = t / 7;                                      \
                const int l   = t - row * 7;                                \
                gv[g] = wb_[row * 49 + l * l + l];                          \
            }                                                               \
        }                                                                   \
        if (lane < 56)                                                      \
            yv = ((const float4*)(y3 + (size_t)(E) * W3OUT))[lane];         \
    } while (0)

    #define COMMIT(B) do {                                                  \
        _Pragma("unroll")                                                   \
        for (int g = 0; g < 6; g++) {                                       \
            const int t = lane + 64 * g;                                    \
            if (t < 343) {                                                  \
                const int row = t / 7;                                      \
                const int l   = t - row * 7;                                \
                wl[wave][B][row * 8 + l] = gv[g];                           \
            }                                                               \
        }                                                                   \
        if (lane < 56) ((float4*)yl[wave][B])[lane] = yv;                   \
    } while (0)

    if (beg < end) {
        GATHER(eids[beg]);
        COMMIT(0);
    }

    int cur = 0;
    for (int ie = beg; ie < end; ie++) {
        if (ie + 1 < end) GATHER(eids[ie + 1]);   // issue early, no LDS deps
        // wave-internal fence: all of this wave's ds_writes (COMMIT) done
        asm volatile("s_waitcnt lgkmcnt(0)" ::: "memory");
        __builtin_amdgcn_sched_barrier(0);

        float yr[7];
        #pragma unroll
        for (int l = 0; l < 7; l++) yr[l] = yl[wave][cur][l * 32 + c];
        #pragma unroll
        for (int r = 0; r < 25; r++) {
            const int i = 2 * r + h;
            if (i < NCOEF) {
                const float4 wa = *(const float4*)(&wl[wave][cur][i * 8]);
                const float4 wb = *(const float4*)(&wl[wave][cur][i * 8 + 4]);
                acc[r] += wa.x * yr[0] + wa.y * yr[1] + wa.z * yr[2] + wa.w * yr[3]
                        + wb.x * yr[4] + wb.y * yr[5] + wb.z * yr[6];
            }
        }
        if (ie + 1 < end) COMMIT(cur ^ 1);        // fills the other buffer
        cur ^= 1;
    }

    #pragma unroll
    for (int r = 0; r < 25; r++) {
        const int i = 2 * r + h;
        if (i < NCOEF)
            out[(size_t)n * (NCOEF * 32) + i * 32 + c] = acc[r];
    }
}

// ---------------------------------------------------------------------------
extern "C" void kernel_launch(void* const* d_in, const int* in_sizes, int n_in,
                              void* d_out, int out_size, void* d_ws, size_t ws_size,
                              hipStream_t stream)
{
    const int*   an   = (const int*)  d_in[0];
    const int*   ei   = (const int*)  d_in[1];
    const float* ed   = (const float*)d_in[2];
    const float* wig  = (const float*)d_in[3];
    const float* semb = (const float*)d_in[4];
    const float* temb = (const float*)d_in[5];
    const float* W1   = (const float*)d_in[6];
    const float* b1   = (const float*)d_in[7];
    const float* g1   = (const float*)d_in[8];
    const float* be1  = (const float*)d_in[9];
    const float* W2   = (const float*)d_in[10];
    const float* b2   = (const float*)d_in[11];
    const float* g2   = (const float*)d_in[12];
    const float* be2  = (const float*)d_in[13];
    const float* W3   = (const float*)d_in[14];
    const float* b3   = (const float*)d_in[15];
    float* out = (float*)d_out;

    char* ws = (char*)d_ws;
    const size_t y3_bytes = (size_t)E_EDGES * W3OUT * sizeof(float); // 71.68 MB
    float* y3     = (float*)ws;
    int*   cnt    = (int*)(ws + y3_bytes);
    int*   offs   = cnt + N_NODES;
    int*   cursor = offs + N_NODES + 1;
    int*   eids   = cursor + N_NODES;
    float* sW1    = (float*)(eids + E_EDGES);
    float* tW1    = sW1 + NELEM * HD;
    const size_t need = y3_bytes +
        sizeof(int) * ((size_t)N_NODES + (N_NODES + 1) + N_NODES + E_EDGES) +
        sizeof(float) * (2 * NELEM * HD);
    if (ws_size < need) return;

    k_pre<<<NELEM, 64, 0, stream>>>(semb, temb, W1, sW1, tW1);
    k_mlp<<<E_EDGES / 16, 256, 0, stream>>>(an, ei, ed, sW1, tW1,
                                            W1, b1, g1, be1,
                                            W2, b2, g2, be2, W3, b3, cnt, y3);
    k_count<<<(E_EDGES + 255) / 256, 256, 0, stream>>>(ei, cnt);
    k_scan<<<1, 1024, 0, stream>>>(cnt, offs, cursor);
    k_scatter<<<(E_EDGES + 255) / 256, 256, 0, stream>>>(ei, cursor, eids);
    k_out<<<N_NODES / 4, 256, 0, stream>>>(wig, y3, offs, eids, out);
}

// Round 12
// 279.924 us; speedup vs baseline: 2.8765x; 1.2574x over previous
//
#include <hip/hip_runtime.h>
#include <hip/hip_bf16.h>
#include <stdint.h>

#define E_EDGES 80000
#define N_NODES 10000
#define HD      64
#define DDIST   128
#define NCOEF   49
#define W3OUT   224   // M0(7) * C_SPH(32)
#define WROW    2401  // 49*49
#define NELEM   90

typedef float  f32x4  __attribute__((ext_vector_type(4)));
typedef short  bf16x8 __attribute__((ext_vector_type(8)));
typedef unsigned int  uint_t;
typedef unsigned short ushort_t;

__device__ __forceinline__ ushort_t f2b(float f) {
    uint_t u = __builtin_bit_cast(uint_t, f);
    return (ushort_t)((u + 0x7FFFu + ((u >> 16) & 1u)) >> 16);   // RNE
}
__device__ __forceinline__ uint_t pack2(float a, float b) {
    return (uint_t)f2b(a) | ((uint_t)f2b(b) << 16);
}

// ---------------------------------------------------------------------------
// k_prep: fold tables (f32, exact r7 math), W1/W2/W3 -> bf16 transposed
// [n][k] layouts, zero cnt.  56 blocks x 256 covers max task (14336).
// ---------------------------------------------------------------------------
__global__ __launch_bounds__(256) void k_prep(
    const float* __restrict__ semb, const float* __restrict__ temb,
    const float* __restrict__ W1, const float* __restrict__ W2,
    const float* __restrict__ W3,
    float* __restrict__ sW1, float* __restrict__ tW1,
    ushort_t* __restrict__ W1T, ushort_t* __restrict__ W2T,
    ushort_t* __restrict__ W3T, int* __restrict__ cnt)
{
    const int gid = blockIdx.x * 256 + threadIdx.x;
    if (gid < NELEM * 64) {
        const int z = gid >> 6, n = gid & 63;
        float sa = 0.f, ta = 0.f;
        #pragma unroll 4
        for (int k = 0; k < 64; k++) {
            sa = fmaf(semb[z * 64 + k], W1[(128 + k) * 64 + n], sa);
            ta = fmaf(temb[z * 64 + k], W1[(192 + k) * 64 + n], ta);
        }
        sW1[z * 64 + n] = sa;
        tW1[z * 64 + n] = ta;
    }
    if (gid < 8192)  { const int n = gid >> 7, k = gid & 127; W1T[gid] = f2b(W1[k * 64 + n]); }
    if (gid < 4096)  { const int n = gid >> 6, k = gid & 63;  W2T[gid] = f2b(W2[k * 64 + n]); }
    if (gid < 14336) { const int n = gid >> 6, k = gid & 63;  W3T[gid] = f2b(W3[k * W3OUT + n]); }
    if (gid < N_NODES) cnt[gid] = 0;
}

// ---------------------------------------------------------------------------
// k_mlp (round 12, MFMA): 64 edges/block, wave w = M-tile rows [16w,16w+16).
// GEMM1 (K=128, fold C-init) -> LN1 -> GEMM2 (K=64) -> LN2 -> GEMM3 (N=224
// in two 112-halves through the shared W-buffer).  All LDS 16B-block
// XOR-swizzled; LN in f32 fragment space; y3 stores 64B-contiguous.
// ---------------------------------------------------------------------------
__global__ __launch_bounds__(256, 3) void k_mlp(
    const int* __restrict__ an, const int* __restrict__ ei,
    const float* __restrict__ ed,
    const float* __restrict__ sW1, const float* __restrict__ tW1,
    const ushort_t* __restrict__ W1T, const ushort_t* __restrict__ W2T,
    const ushort_t* __restrict__ W3T,
    const float* __restrict__ b1, const float* __restrict__ g1,
    const float* __restrict__ be1,
    const float* __restrict__ b2, const float* __restrict__ g2,
    const float* __restrict__ be2,
    const float* __restrict__ b3, float* __restrict__ y3)
{
    __shared__ __align__(16) ushort_t Xs[64 * 128];   // 16 KB
    __shared__ __align__(16) ushort_t Ws[64 * 128];   // 16 KB (W1T/W2T/W3T-half)
    __shared__ __align__(16) ushort_t Hs[64 * 64];    // 8 KB
    __shared__ __align__(16) ushort_t H2s[64 * 64];   // 8 KB

    const int tid  = threadIdx.x;
    const int wave = tid >> 6, lane = tid & 63;
    const int e0   = blockIdx.x * 64;
    const int mo   = wave * 16;
    const int cl   = lane & 15;      // A-row / B-col / D-col within 16
    const int kgr  = lane >> 4;      // k-group (8 elems each)

    // ---- stage X: ed (f32) -> bf16 swizzled [m][kb^(m&15)] ------------------
    {
        const int m = tid >> 2, q = tid & 3;
        const float4* ed4 = (const float4*)(ed + (size_t)(e0 + m) * DDIST);
        #pragma unroll
        for (int j = 0; j < 4; j++) {
            const int kb = q * 4 + j;
            const float4 f0 = ed4[kb * 2];
            const float4 f1 = ed4[kb * 2 + 1];
            uint4 p;
            p.x = pack2(f0.x, f0.y); p.y = pack2(f0.z, f0.w);
            p.z = pack2(f1.x, f1.y); p.w = pack2(f1.z, f1.w);
            *(uint4*)&Xs[m * 128 + ((kb ^ (m & 15)) * 8)] = p;
        }
    }
    // ---- stage W1T (1024 x 16B blocks) --------------------------------------
    {
        const uint4* src = (const uint4*)W1T;
        #pragma unroll
        for (int i = 0; i < 4; i++) {
            const int B = tid + i * 256;
            const int n = B >> 4, kb = B & 15;
            *(uint4*)&Ws[n * 128 + ((kb ^ (n & 15)) * 8)] = src[B];
        }
    }

    // ---- acc C-init from f32 fold tables (exact r7 layer-1 embedding) -------
    f32x4 acc[4];
    {
        const int er0 = e0 + mo + kgr * 4;
        const int4 s4 = *(const int4*)&ei[er0];
        const int4 t4 = *(const int4*)&ei[E_EDGES + er0];
        const int zs0 = an[s4.x], zs1 = an[s4.y], zs2 = an[s4.z], zs3 = an[s4.w];
        const int zt0 = an[t4.x], zt1 = an[t4.y], zt2 = an[t4.z], zt3 = an[t4.w];
        #pragma unroll
        for (int nf = 0; nf < 4; nf++) {
            const int col = nf * 16 + cl;
            acc[nf][0] = sW1[zs0 * 64 + col] + tW1[zt0 * 64 + col];
            acc[nf][1] = sW1[zs1 * 64 + col] + tW1[zt1 * 64 + col];
            acc[nf][2] = sW1[zs2 * 64 + col] + tW1[zt2 * 64 + col];
            acc[nf][3] = sW1[zs3 * 64 + col] + tW1[zt3 * 64 + col];
        }
    }
    __syncthreads();

    // ---- GEMM1: K=128 --------------------------------------------------------
    {
        const int m = mo + cl;
        #pragma unroll
        for (int kc = 0; kc < 4; kc++) {
            const int kb = kc * 4 + kgr;
            const bf16x8 a = *(const bf16x8*)&Xs[m * 128 + ((kb ^ (m & 15)) * 8)];
            #pragma unroll
            for (int nf = 0; nf < 4; nf++) {
                const int n = nf * 16 + cl;
                const bf16x8 b = *(const bf16x8*)&Ws[n * 128 + ((kb ^ (n & 15)) * 8)];
                acc[nf] = __builtin_amdgcn_mfma_f32_16x16x32_bf16(a, b, acc[nf], 0, 0, 0);
            }
        }
    }

    // ---- LN1 + silu -> Hs ----------------------------------------------------
    {
        float b1v[4], g1v[4], e1v[4];
        #pragma unroll
        for (int nf = 0; nf < 4; nf++) {
            b1v[nf] = b1[nf * 16 + cl];
            g1v[nf] = g1[nf * 16 + cl];
            e1v[nf] = be1[nf * 16 + cl];
        }
        #pragma unroll
        for (int nf = 0; nf < 4; nf++)
            #pragma unroll
            for (int r = 0; r < 4; r++) acc[nf][r] += b1v[nf];
        #pragma unroll
        for (int r = 0; r < 4; r++) {
            float s = acc[0][r] + acc[1][r] + acc[2][r] + acc[3][r];
            float q = acc[0][r]*acc[0][r] + acc[1][r]*acc[1][r]
                    + acc[2][r]*acc[2][r] + acc[3][r]*acc[3][r];
            s += __shfl_xor(s, 1, 64); q += __shfl_xor(q, 1, 64);
            s += __shfl_xor(s, 2, 64); q += __shfl_xor(q, 2, 64);
            s += __shfl_xor(s, 4, 64); q += __shfl_xor(q, 4, 64);
            s += __shfl_xor(s, 8, 64); q += __shfl_xor(q, 8, 64);
            const float mu  = s * (1.f / 64.f);
            const float var = fmaxf(q * (1.f / 64.f) - mu * mu, 0.f);
            const float rstd = rsqrtf(var + 1e-5f);
            const int m_h = mo + kgr * 4 + r;
            #pragma unroll
            for (int nf = 0; nf < 4; nf++) {
                const float t = (acc[nf][r] - mu) * rstd * g1v[nf] + e1v[nf];
                const float h = t / (1.f + expf(-t));
                const int ch = nf * 16 + cl;
                Hs[m_h * 64 + (((ch >> 3) ^ (m_h & 7)) * 8) + (ch & 7)] = f2b(h);
            }
        }
    }
    __syncthreads();

    // ---- stage W2T (512 x 16B blocks) ---------------------------------------
    {
        const uint4* src = (const uint4*)W2T;
        #pragma unroll
        for (int i = 0; i < 2; i++) {
            const int B = tid + i * 256;
            const int n = B >> 3, kb = B & 7;
            *(uint4*)&Ws[n * 64 + ((kb ^ (n & 7)) * 8)] = src[B];
        }
    }
    __syncthreads();

    // ---- GEMM2: K=64 ---------------------------------------------------------
    f32x4 acc2[4];
    {
        const f32x4 z = {0.f, 0.f, 0.f, 0.f};
        acc2[0] = z; acc2[1] = z; acc2[2] = z; acc2[3] = z;
        const int m = mo + cl;
        #pragma unroll
        for (int kc = 0; kc < 2; kc++) {
            const int kb = kc * 4 + kgr;
            const bf16x8 a = *(const bf16x8*)&Hs[m * 64 + ((kb ^ (m & 7)) * 8)];
            #pragma unroll
            for (int nf = 0; nf < 4; nf++) {
                const int n = nf * 16 + cl;
                const bf16x8 b = *(const bf16x8*)&Ws[n * 64 + ((kb ^ (n & 7)) * 8)];
                acc2[nf] = __builtin_amdgcn_mfma_f32_16x16x32_bf16(a, b, acc2[nf], 0, 0, 0);
            }
        }
    }

    // ---- LN2 + silu -> H2s ---------------------------------------------------
    {
        float b2v[4], g2v[4], e2v[4];
        #pragma unroll
        for (int nf = 0; nf < 4; nf++) {
            b2v[nf] = b2[nf * 16 + cl];
            g2v[nf] = g2[nf * 16 + cl];
            e2v[nf] = be2[nf * 16 + cl];
        }
        #pragma unroll
        for (int nf = 0; nf < 4; nf++)
            #pragma unroll
            for (int r = 0; r < 4; r++) acc2[nf][r] += b2v[nf];
        #pragma unroll
        for (int r = 0; r < 4; r++) {
            float s = acc2[0][r] + acc2[1][r] + acc2[2][r] + acc2[3][r];
            float q = acc2[0][r]*acc2[0][r] + acc2[1][r]*acc2[1][r]
                    + acc2[2][r]*acc2[2][r] + acc2[3][r]*acc2[3][r];
            s += __shfl_xor(s, 1, 64); q += __shfl_xor(q, 1, 64);
            s += __shfl_xor(s, 2, 64); q += __shfl_xor(q, 2, 64);
            s += __shfl_xor(s, 4, 64); q += __shfl_xor(q, 4, 64);
            s += __shfl_xor(s, 8, 64); q += __shfl_xor(q, 8, 64);
            const float mu  = s * (1.f / 64.f);
            const float var = fmaxf(q * (1.f / 64.f) - mu * mu, 0.f);
            const float rstd = rsqrtf(var + 1e-5f);
            const int m_h = mo + kgr * 4 + r;
            #pragma unroll
            for (int nf = 0; nf < 4; nf++) {
                const float t = (acc2[nf][r] - mu) * rstd * g2v[nf] + e2v[nf];
                const float h = t / (1.f + expf(-t));
                const int ch = nf * 16 + cl;
                H2s[m_h * 64 + (((ch >> 3) ^ (m_h & 7)) * 8) + (ch & 7)] = f2b(h);
            }
        }
    }
    __syncthreads();

    // ---- GEMM3 in two N=112 halves through Ws --------------------------------
    const int er0 = e0 + mo + kgr * 4;
    #pragma unroll
    for (int half = 0; half < 2; half++) {
        // stage W3T rows [half*112, half*112+112) : 896 x 16B blocks
        {
            const uint4* src = (const uint4*)W3T;
            #pragma unroll
            for (int i = 0; i < 4; i++) {
                const int B = tid + i * 256;
                if (B < 896) {
                    const int nn = B >> 3, kb = B & 7;
                    *(uint4*)&Ws[nn * 64 + ((kb ^ (nn & 7)) * 8)] = src[half * 896 + B];
                }
            }
        }
        __syncthreads();

        f32x4 acc3[7];
        {
            const f32x4 z = {0.f, 0.f, 0.f, 0.f};
            #pragma unroll
            for (int nf = 0; nf < 7; nf++) acc3[nf] = z;
        }
        const int m = mo + cl;
        #pragma unroll
        for (int kc = 0; kc < 2; kc++) {
            const int kb = kc * 4 + kgr;
            const bf16x8 a = *(const bf16x8*)&H2s[m * 64 + ((kb ^ (m & 7)) * 8)];
            #pragma unroll
            for (int nf = 0; nf < 7; nf++) {
                const int nn = nf * 16 + cl;
                const bf16x8 b = *(const bf16x8*)&Ws[nn * 64 + ((kb ^ (nn & 7)) * 8)];
                acc3[nf] = __builtin_amdgcn_mfma_f32_16x16x32_bf16(a, b, acc3[nf], 0, 0, 0);
            }
        }
        #pragma unroll
        for (int nf = 0; nf < 7; nf++) {
            const int ch = half * 112 + nf * 16 + cl;
            const float bv = b3[ch];
            #pragma unroll
            for (int r = 0; r < 4; r++)
                y3[(size_t)(er0 + r) * W3OUT + ch] =
                    (acc3[nf][r] + bv) * (1.0f / 5.862f);
        }
        __syncthreads();   // done reading Ws before next half overwrites
    }
}

// ---------------------------------------------------------------------------
// CSR build (frozen)
// ---------------------------------------------------------------------------
__global__ void k_count(const int* __restrict__ ei, int* __restrict__ cnt) {
    const int e = blockIdx.x * 256 + threadIdx.x;
    if (e < E_EDGES) atomicAdd(&cnt[ei[E_EDGES + e]], 1);
}

__global__ __launch_bounds__(1024) void k_scan(const int* __restrict__ cnt,
                                               int* __restrict__ offs,
                                               int* __restrict__ cursor) {
    __shared__ int wsum[16];
    __shared__ int carry_s;
    const int tid  = threadIdx.x;
    const int lane = tid & 63;
    const int wid  = tid >> 6;
    if (tid == 0) carry_s = 0;
    __syncthreads();
    for (int base = 0; base < N_NODES; base += 1024) {
        const int idx = base + tid;
        const int v = (idx < N_NODES) ? cnt[idx] : 0;
        int s = v;
        #pragma unroll
        for (int off = 1; off < 64; off <<= 1) {
            const int t = __shfl_up(s, off, 64);
            if (lane >= off) s += t;
        }
        if (lane == 63) wsum[wid] = s;
        __syncthreads();
        if (wid == 0) {
            const int t = (lane < 16) ? wsum[lane] : 0;
            int ss = t;
            #pragma unroll
            for (int off = 1; off < 16; off <<= 1) {
                const int u = __shfl_up(ss, off, 64);
                if (lane >= off) ss += u;
            }
            if (lane < 16) wsum[lane] = ss - t;
        }
        __syncthreads();
        const int carry = carry_s;
        const int excl = carry + wsum[wid] + s - v;
        if (idx < N_NODES) { offs[idx] = excl; cursor[idx] = excl; }
        __syncthreads();
        if (tid == 1023) carry_s = carry + wsum[15] + s;
    }
    __syncthreads();
    if (tid == 0) offs[N_NODES] = carry_s;
}

__global__ void k_scatter(const int* __restrict__ ei, int* __restrict__ cursor,
                          int* __restrict__ eids) {
    const int e = blockIdx.x * 256 + threadIdx.x;
    if (e < E_EDGES) {
        const int pos = atomicAdd(&cursor[ei[E_EDGES + e]], 1);
        eids[pos] = e;
    }
}

// ---------------------------------------------------------------------------
// k_out (FROZEN from round 11): wave per node, barrier-free gather.
// ---------------------------------------------------------------------------
__global__ __launch_bounds__(256) void k_out(
    const float* __restrict__ wig, const float* __restrict__ y3,
    const int* __restrict__ offs, const int* __restrict__ eids,
    float* __restrict__ out)
{
    __shared__ __align__(16) float wl[4][2][400];
    __shared__ __align__(16) float yl[4][2][224];
    const int tid  = threadIdx.x;
    const int wave = tid >> 6;
    const int lane = tid & 63;
    const int n    = blockIdx.x * 4 + wave;
    const int c    = lane & 31;
    const int h    = lane >> 5;
    const int beg  = offs[n];
    const int end  = offs[n + 1];

    float acc[25];
    #pragma unroll
    for (int r = 0; r < 25; r++) acc[r] = 0.f;

    float gv[6];
    float4 yv;

    #define GATHER(E) do {                                                  \
        const float* __restrict__ wb_ = wig + (size_t)(E) * WROW;           \
        _Pragma("unroll")                                                   \
        for (int g = 0; g < 6; g++) {                                       \
            const int t = lane + 64 * g;                                    \
            if (t < 343) {                                                  \
                const int row = t / 7;                                      \
                const int l   = t - row * 7;                                \
                gv[g] = wb_[row * 49 + l * l + l];                          \
            }                                                               \
        }                                                                   \
        if (lane < 56)                                                      \
            yv = ((const float4*)(y3 + (size_t)(E) * W3OUT))[lane];         \
    } while (0)

    #define COMMIT(B) do {                                                  \
        _Pragma("unroll")                                                   \
        for (int g = 0; g < 6; g++) {                                       \
            const int t = lane + 64 * g;                                    \
            if (t < 343) {                                                  \
                const int row = t / 7;                                      \
                const int l   = t - row * 7;                                \
                wl[wave][B][row * 8 + l] = gv[g];                           \
            }                                                               \
        }                                                                   \
        if (lane < 56) ((float4*)yl[wave][B])[lane] = yv;                   \
    } while (0)

    if (beg < end) {
        GATHER(eids[beg]);
        COMMIT(0);
    }

    int cur = 0;
    for (int ie = beg; ie < end; ie++) {
        if (ie + 1 < end) GATHER(eids[ie + 1]);
        asm volatile("s_waitcnt lgkmcnt(0)" ::: "memory");
        __builtin_amdgcn_sched_barrier(0);

        float yr[7];
        #pragma unroll
        for (int l = 0; l < 7; l++) yr[l] = yl[wave][cur][l * 32 + c];
        #pragma unroll
        for (int r = 0; r < 25; r++) {
            const int i = 2 * r + h;
            if (i < NCOEF) {
                const float4 wa = *(const float4*)(&wl[wave][cur][i * 8]);
                const float4 wb = *(const float4*)(&wl[wave][cur][i * 8 + 4]);
                acc[r] += wa.x * yr[0] + wa.y * yr[1] + wa.z * yr[2] + wa.w * yr[3]
                        + wb.x * yr[4] + wb.y * yr[5] + wb.z * yr[6];
            }
        }
        if (ie + 1 < end) COMMIT(cur ^ 1);
        cur ^= 1;
    }

    #pragma unroll
    for (int r = 0; r < 25; r++) {
        const int i = 2 * r + h;
        if (i < NCOEF)
            out[(size_t)n * (NCOEF * 32) + i * 32 + c] = acc[r];
    }
}

// ---------------------------------------------------------------------------
extern "C" void kernel_launch(void* const* d_in, const int* in_sizes, int n_in,
                              void* d_out, int out_size, void* d_ws, size_t ws_size,
                              hipStream_t stream)
{
    const int*   an   = (const int*)  d_in[0];
    const int*   ei   = (const int*)  d_in[1];
    const float* ed   = (const float*)d_in[2];
    const float* wig  = (const float*)d_in[3];
    const float* semb = (const float*)d_in[4];
    const float* temb = (const float*)d_in[5];
    const float* W1   = (const float*)d_in[6];
    const float* b1   = (const float*)d_in[7];
    const float* g1   = (const float*)d_in[8];
    const float* be1  = (const float*)d_in[9];
    const float* W2   = (const float*)d_in[10];
    const float* b2   = (const float*)d_in[11];
    const float* g2   = (const float*)d_in[12];
    const float* be2  = (const float*)d_in[13];
    const float* W3   = (const float*)d_in[14];
    const float* b3   = (const float*)d_in[15];
    float* out = (float*)d_out;

    uintptr_t p = (uintptr_t)d_ws;
    #define ALLOC(ptr, type, count) \
        p = (p + 15) & ~(uintptr_t)15; type* ptr = (type*)p; p += sizeof(type) * (count)
    ALLOC(y3,     float,    (size_t)E_EDGES * W3OUT);
    ALLOC(cnt,    int,      N_NODES);
    ALLOC(offs,   int,      N_NODES + 1);
    ALLOC(cursor, int,      N_NODES);
    ALLOC(eids,   int,      E_EDGES);
    ALLOC(sW1,    float,    NELEM * HD);
    ALLOC(tW1,    float,    NELEM * HD);
    ALLOC(W1T,    ushort_t, 64 * 128);
    ALLOC(W2T,    ushort_t, 64 * 64);
    ALLOC(W3T,    ushort_t, 224 * 64);
    #undef ALLOC
    if (p - (uintptr_t)d_ws > ws_size) return;

    k_prep<<<56, 256, 0, stream>>>(semb, temb, W1, W2, W3,
                                   sW1, tW1, W1T, W2T, W3T, cnt);
    k_mlp<<<E_EDGES / 64, 256, 0, stream>>>(an, ei, ed, sW1, tW1,
                                            W1T, W2T, W3T,
                                            b1, g1, be1, b2, g2, be2,
                                            b3, y3);
    k_count<<<(E_EDGES + 255) / 256, 256, 0, stream>>>(ei, cnt);
    k_scan<<<1, 1024, 0, stream>>>(cnt, offs, cursor);
    k_scatter<<<(E_EDGES + 255) / 256, 256, 0, stream>>>(ei, cursor, eids);
    k_out<<<N_NODES / 4, 256, 0, stream>>>(wig, y3, offs, eids, out);
}

// Round 13
// 265.489 us; speedup vs baseline: 3.0329x; 1.0544x over previous
//
#include <hip/hip_runtime.h>
#include <hip/hip_bf16.h>
#include <stdint.h>

#define E_EDGES 80000
#define N_NODES 10000
#define HD      64
#define DDIST   128
#define NCOEF   49
#define W3OUT   224   // M0(7) * C_SPH(32)
#define WROW    2401  // 49*49
#define NELEM   90

typedef float  f32x4  __attribute__((ext_vector_type(4)));
typedef short  bf16x8 __attribute__((ext_vector_type(8)));
typedef unsigned int  uint_t;
typedef unsigned short ushort_t;

__device__ __forceinline__ ushort_t f2b(float f) {
    uint_t u = __builtin_bit_cast(uint_t, f);
    return (ushort_t)((u + 0x7FFFu + ((u >> 16) & 1u)) >> 16);   // RNE
}
__device__ __forceinline__ uint_t pack2(float a, float b) {
    return (uint_t)f2b(a) | ((uint_t)f2b(b) << 16);
}
__device__ __forceinline__ float b2f(uint_t v) {
    return __builtin_bit_cast(float, v << 16);
}

// ---------------------------------------------------------------------------
// k_prep: fold tables (f32), W1/W2/W3 -> bf16 transposed [n][k]; zero cnt.
// ---------------------------------------------------------------------------
__global__ __launch_bounds__(256) void k_prep(
    const float* __restrict__ semb, const float* __restrict__ temb,
    const float* __restrict__ W1, const float* __restrict__ W2,
    const float* __restrict__ W3,
    float* __restrict__ sW1, float* __restrict__ tW1,
    ushort_t* __restrict__ W1T, ushort_t* __restrict__ W2T,
    ushort_t* __restrict__ W3T, int* __restrict__ cnt)
{
    const int gid = blockIdx.x * 256 + threadIdx.x;
    if (gid < NELEM * 64) {
        const int z = gid >> 6, n = gid & 63;
        float sa = 0.f, ta = 0.f;
        #pragma unroll 4
        for (int k = 0; k < 64; k++) {
            sa = fmaf(semb[z * 64 + k], W1[(128 + k) * 64 + n], sa);
            ta = fmaf(temb[z * 64 + k], W1[(192 + k) * 64 + n], ta);
        }
        sW1[z * 64 + n] = sa;
        tW1[z * 64 + n] = ta;
    }
    if (gid < 8192)  { const int n = gid >> 7, k = gid & 127; W1T[gid] = f2b(W1[k * 64 + n]); }
    if (gid < 4096)  { const int n = gid >> 6, k = gid & 63;  W2T[gid] = f2b(W2[k * 64 + n]); }
    if (gid < 14336) { const int n = gid >> 6, k = gid & 63;  W3T[gid] = f2b(W3[k * W3OUT + n]); }
    if (gid < N_NODES) cnt[gid] = 0;
}

// ---------------------------------------------------------------------------
// k_mlp (r12 MFMA version; only change: y3 stored as bf16).
// ---------------------------------------------------------------------------
__global__ __launch_bounds__(256, 3) void k_mlp(
    const int* __restrict__ an, const int* __restrict__ ei,
    const float* __restrict__ ed,
    const float* __restrict__ sW1, const float* __restrict__ tW1,
    const ushort_t* __restrict__ W1T, const ushort_t* __restrict__ W2T,
    const ushort_t* __restrict__ W3T,
    const float* __restrict__ b1, const float* __restrict__ g1,
    const float* __restrict__ be1,
    const float* __restrict__ b2, const float* __restrict__ g2,
    const float* __restrict__ be2,
    const float* __restrict__ b3, ushort_t* __restrict__ y3)
{
    __shared__ __align__(16) ushort_t Xs[64 * 128];
    __shared__ __align__(16) ushort_t Ws[64 * 128];
    __shared__ __align__(16) ushort_t Hs[64 * 64];
    __shared__ __align__(16) ushort_t H2s[64 * 64];

    const int tid  = threadIdx.x;
    const int wave = tid >> 6, lane = tid & 63;
    const int e0   = blockIdx.x * 64;
    const int mo   = wave * 16;
    const int cl   = lane & 15;
    const int kgr  = lane >> 4;

    {
        const int m = tid >> 2, q = tid & 3;
        const float4* ed4 = (const float4*)(ed + (size_t)(e0 + m) * DDIST);
        #pragma unroll
        for (int j = 0; j < 4; j++) {
            const int kb = q * 4 + j;
            const float4 f0 = ed4[kb * 2];
            const float4 f1 = ed4[kb * 2 + 1];
            uint4 p;
            p.x = pack2(f0.x, f0.y); p.y = pack2(f0.z, f0.w);
            p.z = pack2(f1.x, f1.y); p.w = pack2(f1.z, f1.w);
            *(uint4*)&Xs[m * 128 + ((kb ^ (m & 15)) * 8)] = p;
        }
    }
    {
        const uint4* src = (const uint4*)W1T;
        #pragma unroll
        for (int i = 0; i < 4; i++) {
            const int B = tid + i * 256;
            const int n = B >> 4, kb = B & 15;
            *(uint4*)&Ws[n * 128 + ((kb ^ (n & 15)) * 8)] = src[B];
        }
    }

    f32x4 acc[4];
    {
        const int er0 = e0 + mo + kgr * 4;
        const int4 s4 = *(const int4*)&ei[er0];
        const int4 t4 = *(const int4*)&ei[E_EDGES + er0];
        const int zs0 = an[s4.x], zs1 = an[s4.y], zs2 = an[s4.z], zs3 = an[s4.w];
        const int zt0 = an[t4.x], zt1 = an[t4.y], zt2 = an[t4.z], zt3 = an[t4.w];
        #pragma unroll
        for (int nf = 0; nf < 4; nf++) {
            const int col = nf * 16 + cl;
            acc[nf][0] = sW1[zs0 * 64 + col] + tW1[zt0 * 64 + col];
            acc[nf][1] = sW1[zs1 * 64 + col] + tW1[zt1 * 64 + col];
            acc[nf][2] = sW1[zs2 * 64 + col] + tW1[zt2 * 64 + col];
            acc[nf][3] = sW1[zs3 * 64 + col] + tW1[zt3 * 64 + col];
        }
    }
    __syncthreads();

    {
        const int m = mo + cl;
        #pragma unroll
        for (int kc = 0; kc < 4; kc++) {
            const int kb = kc * 4 + kgr;
            const bf16x8 a = *(const bf16x8*)&Xs[m * 128 + ((kb ^ (m & 15)) * 8)];
            #pragma unroll
            for (int nf = 0; nf < 4; nf++) {
                const int n = nf * 16 + cl;
                const bf16x8 b = *(const bf16x8*)&Ws[n * 128 + ((kb ^ (n & 15)) * 8)];
                acc[nf] = __builtin_amdgcn_mfma_f32_16x16x32_bf16(a, b, acc[nf], 0, 0, 0);
            }
        }
    }

    {
        float b1v[4], g1v[4], e1v[4];
        #pragma unroll
        for (int nf = 0; nf < 4; nf++) {
            b1v[nf] = b1[nf * 16 + cl];
            g1v[nf] = g1[nf * 16 + cl];
            e1v[nf] = be1[nf * 16 + cl];
        }
        #pragma unroll
        for (int nf = 0; nf < 4; nf++)
            #pragma unroll
            for (int r = 0; r < 4; r++) acc[nf][r] += b1v[nf];
        #pragma unroll
        for (int r = 0; r < 4; r++) {
            float s = acc[0][r] + acc[1][r] + acc[2][r] + acc[3][r];
            float q = acc[0][r]*acc[0][r] + acc[1][r]*acc[1][r]
                    + acc[2][r]*acc[2][r] + acc[3][r]*acc[3][r];
            s += __shfl_xor(s, 1, 64); q += __shfl_xor(q, 1, 64);
            s += __shfl_xor(s, 2, 64); q += __shfl_xor(q, 2, 64);
            s += __shfl_xor(s, 4, 64); q += __shfl_xor(q, 4, 64);
            s += __shfl_xor(s, 8, 64); q += __shfl_xor(q, 8, 64);
            const float mu  = s * (1.f / 64.f);
            const float var = fmaxf(q * (1.f / 64.f) - mu * mu, 0.f);
            const float rstd = rsqrtf(var + 1e-5f);
            const int m_h = mo + kgr * 4 + r;
            #pragma unroll
            for (int nf = 0; nf < 4; nf++) {
                const float t = (acc[nf][r] - mu) * rstd * g1v[nf] + e1v[nf];
                const float h = t / (1.f + expf(-t));
                const int ch = nf * 16 + cl;
                Hs[m_h * 64 + (((ch >> 3) ^ (m_h & 7)) * 8) + (ch & 7)] = f2b(h);
            }
        }
    }
    __syncthreads();

    {
        const uint4* src = (const uint4*)W2T;
        #pragma unroll
        for (int i = 0; i < 2; i++) {
            const int B = tid + i * 256;
            const int n = B >> 3, kb = B & 7;
            *(uint4*)&Ws[n * 64 + ((kb ^ (n & 7)) * 8)] = src[B];
        }
    }
    __syncthreads();

    f32x4 acc2[4];
    {
        const f32x4 z = {0.f, 0.f, 0.f, 0.f};
        acc2[0] = z; acc2[1] = z; acc2[2] = z; acc2[3] = z;
        const int m = mo + cl;
        #pragma unroll
        for (int kc = 0; kc < 2; kc++) {
            const int kb = kc * 4 + kgr;
            const bf16x8 a = *(const bf16x8*)&Hs[m * 64 + ((kb ^ (m & 7)) * 8)];
            #pragma unroll
            for (int nf = 0; nf < 4; nf++) {
                const int n = nf * 16 + cl;
                const bf16x8 b = *(const bf16x8*)&Ws[n * 64 + ((kb ^ (n & 7)) * 8)];
                acc2[nf] = __builtin_amdgcn_mfma_f32_16x16x32_bf16(a, b, acc2[nf], 0, 0, 0);
            }
        }
    }

    {
        float b2v[4], g2v[4], e2v[4];
        #pragma unroll
        for (int nf = 0; nf < 4; nf++) {
            b2v[nf] = b2[nf * 16 + cl];
            g2v[nf] = g2[nf * 16 + cl];
            e2v[nf] = be2[nf * 16 + cl];
        }
        #pragma unroll
        for (int nf = 0; nf < 4; nf++)
            #pragma unroll
            for (int r = 0; r < 4; r++) acc2[nf][r] += b2v[nf];
        #pragma unroll
        for (int r = 0; r < 4; r++) {
            float s = acc2[0][r] + acc2[1][r] + acc2[2][r] + acc2[3][r];
            float q = acc2[0][r]*acc2[0][r] + acc2[1][r]*acc2[1][r]
                    + acc2[2][r]*acc2[2][r] + acc2[3][r]*acc2[3][r];
            s += __shfl_xor(s, 1, 64); q += __shfl_xor(q, 1, 64);
            s += __shfl_xor(s, 2, 64); q += __shfl_xor(q, 2, 64);
            s += __shfl_xor(s, 4, 64); q += __shfl_xor(q, 4, 64);
            s += __shfl_xor(s, 8, 64); q += __shfl_xor(q, 8, 64);
            const float mu  = s * (1.f / 64.f);
            const float var = fmaxf(q * (1.f / 64.f) - mu * mu, 0.f);
            const float rstd = rsqrtf(var + 1e-5f);
            const int m_h = mo + kgr * 4 + r;
            #pragma unroll
            for (int nf = 0; nf < 4; nf++) {
                const float t = (acc2[nf][r] - mu) * rstd * g2v[nf] + e2v[nf];
                const float h = t / (1.f + expf(-t));
                const int ch = nf * 16 + cl;
                H2s[m_h * 64 + (((ch >> 3) ^ (m_h & 7)) * 8) + (ch & 7)] = f2b(h);
            }
        }
    }
    __syncthreads();

    const int er0 = e0 + mo + kgr * 4;
    #pragma unroll
    for (int half = 0; half < 2; half++) {
        {
            const uint4* src = (const uint4*)W3T;
            #pragma unroll
            for (int i = 0; i < 4; i++) {
                const int B = tid + i * 256;
                if (B < 896) {
                    const int nn = B >> 3, kb = B & 7;
                    *(uint4*)&Ws[nn * 64 + ((kb ^ (nn & 7)) * 8)] = src[half * 896 + B];
                }
            }
        }
        __syncthreads();

        f32x4 acc3[7];
        {
            const f32x4 z = {0.f, 0.f, 0.f, 0.f};
            #pragma unroll
            for (int nf = 0; nf < 7; nf++) acc3[nf] = z;
        }
        const int m = mo + cl;
        #pragma unroll
        for (int kc = 0; kc < 2; kc++) {
            const int kb = kc * 4 + kgr;
            const bf16x8 a = *(const bf16x8*)&H2s[m * 64 + ((kb ^ (m & 7)) * 8)];
            #pragma unroll
            for (int nf = 0; nf < 7; nf++) {
                const int nn = nf * 16 + cl;
                const bf16x8 b = *(const bf16x8*)&Ws[nn * 64 + ((kb ^ (nn & 7)) * 8)];
                acc3[nf] = __builtin_amdgcn_mfma_f32_16x16x32_bf16(a, b, acc3[nf], 0, 0, 0);
            }
        }
        #pragma unroll
        for (int nf = 0; nf < 7; nf++) {
            const int ch = half * 112 + nf * 16 + cl;
            const float bv = b3[ch];
            #pragma unroll
            for (int r = 0; r < 4; r++)
                y3[(size_t)(er0 + r) * W3OUT + ch] =
                    f2b((acc3[nf][r] + bv) * (1.0f / 5.862f));
        }
        __syncthreads();
    }
}

// ---------------------------------------------------------------------------
// CSR build (frozen)
// ---------------------------------------------------------------------------
__global__ void k_count(const int* __restrict__ ei, int* __restrict__ cnt) {
    const int e = blockIdx.x * 256 + threadIdx.x;
    if (e < E_EDGES) atomicAdd(&cnt[ei[E_EDGES + e]], 1);
}

__global__ __launch_bounds__(1024) void k_scan(const int* __restrict__ cnt,
                                               int* __restrict__ offs,
                                               int* __restrict__ cursor) {
    __shared__ int wsum[16];
    __shared__ int carry_s;
    const int tid  = threadIdx.x;
    const int lane = tid & 63;
    const int wid  = tid >> 6;
    if (tid == 0) carry_s = 0;
    __syncthreads();
    for (int base = 0; base < N_NODES; base += 1024) {
        const int idx = base + tid;
        const int v = (idx < N_NODES) ? cnt[idx] : 0;
        int s = v;
        #pragma unroll
        for (int off = 1; off < 64; off <<= 1) {
            const int t = __shfl_up(s, off, 64);
            if (lane >= off) s += t;
        }
        if (lane == 63) wsum[wid] = s;
        __syncthreads();
        if (wid == 0) {
            const int t = (lane < 16) ? wsum[lane] : 0;
            int ss = t;
            #pragma unroll
            for (int off = 1; off < 16; off <<= 1) {
                const int u = __shfl_up(ss, off, 64);
                if (lane >= off) ss += u;
            }
            if (lane < 16) wsum[lane] = ss - t;
        }
        __syncthreads();
        const int carry = carry_s;
        const int excl = carry + wsum[wid] + s - v;
        if (idx < N_NODES) { offs[idx] = excl; cursor[idx] = excl; }
        __syncthreads();
        if (tid == 1023) carry_s = carry + wsum[15] + s;
    }
    __syncthreads();
    if (tid == 0) offs[N_NODES] = carry_s;
}

__global__ void k_scatter(const int* __restrict__ ei, int* __restrict__ cursor,
                          int* __restrict__ eids) {
    const int e = blockIdx.x * 256 + threadIdx.x;
    if (e < E_EDGES) {
        const int pos = atomicAdd(&cursor[ei[E_EDGES + e]], 1);
        eids[pos] = e;
    }
}

// ---------------------------------------------------------------------------
// k_out (round 13): wave per node, barrier-free, DEPTH-2 pipeline with two
// named register sets (static indexing), bf16 y3.
// ---------------------------------------------------------------------------
__global__ __launch_bounds__(256) void k_out(
    const float* __restrict__ wig, const ushort_t* __restrict__ y3,
    const int* __restrict__ offs, const int* __restrict__ eids,
    float* __restrict__ out)
{
    __shared__ __align__(16) float wl[4][2][400];
    __shared__ __align__(16) float yl[4][2][224];
    const int tid  = threadIdx.x;
    const int wave = tid >> 6;
    const int lane = tid & 63;
    const int n    = blockIdx.x * 4 + wave;
    const int c    = lane & 31;
    const int h    = lane >> 5;
    const int beg  = offs[n];
    const int end  = offs[n + 1];

    float acc[25];
    #pragma unroll
    for (int r = 0; r < 25; r++) acc[r] = 0.f;

    float gvA[6], gvB[6];
    uint2 yvA, yvB;

    #define GATHER(S, E) do {                                               \
        const float* __restrict__ wb_ = wig + (size_t)(E) * WROW;           \
        _Pragma("unroll")                                                   \
        for (int g = 0; g < 6; g++) {                                       \
            const int t = lane + 64 * g;                                    \
            if (t < 343) {                                                  \
                const int row = t / 7;                                      \
                const int l   = t - row * 7;                                \
                gv##S[g] = wb_[row * 49 + l * l + l];                       \
            }                                                               \
        }                                                                   \
        if (lane < 56)                                                      \
            yv##S = ((const uint2*)(y3 + (size_t)(E) * W3OUT))[lane];       \
    } while (0)

    #define COMMIT(S, B) do {                                               \
        _Pragma("unroll")                                                   \
        for (int g = 0; g < 6; g++) {                                       \
            const int t = lane + 64 * g;                                    \
            if (t < 343) {                                                  \
                const int row = t / 7;                                      \
                const int l   = t - row * 7;                                \
                wl[wave][B][row * 8 + l] = gv##S[g];                        \
            }                                                               \
        }                                                                   \
        if (lane < 56) {                                                    \
            float4 yf;                                                      \
            yf.x = b2f(yv##S.x & 0xffffu);                                  \
            yf.y = b2f(yv##S.x >> 16);                                      \
            yf.z = b2f(yv##S.y & 0xffffu);                                  \
            yf.w = b2f(yv##S.y >> 16);                                      \
            ((float4*)yl[wave][B])[lane] = yf;                              \
        }                                                                   \
    } while (0)

    #define FENCE() do {                                                    \
        asm volatile("s_waitcnt lgkmcnt(0)" ::: "memory");                  \
        __builtin_amdgcn_sched_barrier(0);                                  \
    } while (0)

    #define COMPUTE(B) do {                                                 \
        float yr[7];                                                        \
        _Pragma("unroll")                                                   \
        for (int l = 0; l < 7; l++) yr[l] = yl[wave][B][l * 32 + c];        \
        _Pragma("unroll")                                                   \
        for (int r = 0; r < 25; r++) {                                      \
            const int i = 2 * r + h;                                        \
            if (i < NCOEF) {                                                \
                const float4 wa = *(const float4*)(&wl[wave][B][i * 8]);    \
                const float4 wb = *(const float4*)(&wl[wave][B][i * 8 + 4]);\
                acc[r] += wa.x * yr[0] + wa.y * yr[1] + wa.z * yr[2]        \
                        + wa.w * yr[3] + wb.x * yr[4] + wb.y * yr[5]        \
                        + wb.z * yr[6];                                     \
            }                                                               \
        }                                                                   \
    } while (0)

    if (beg < end)     GATHER(A, eids[beg]);
    if (beg + 1 < end) GATHER(B, eids[beg + 1]);
    if (beg < end)     COMMIT(A, 0);     // waits only on RA (RB stays in flight)

    for (int ie = beg; ie < end; ie += 2) {
        // ---- edge ie (LDS buf 0) ----
        if (ie + 2 < end) GATHER(A, eids[ie + 2]);
        FENCE();
        COMPUTE(0);
        if (ie + 1 < end) COMMIT(B, 1);
        // ---- edge ie+1 (LDS buf 1) ----
        if (ie + 1 < end) {
            if (ie + 3 < end) GATHER(B, eids[ie + 3]);
            FENCE();
            COMPUTE(1);
            if (ie + 2 < end) COMMIT(A, 0);
        }
    }

    #pragma unroll
    for (int r = 0; r < 25; r++) {
        const int i = 2 * r + h;
        if (i < NCOEF)
            out[(size_t)n * (NCOEF * 32) + i * 32 + c] = acc[r];
    }
}

// ---------------------------------------------------------------------------
extern "C" void kernel_launch(void* const* d_in, const int* in_sizes, int n_in,
                              void* d_out, int out_size, void* d_ws, size_t ws_size,
                              hipStream_t stream)
{
    const int*   an   = (const int*)  d_in[0];
    const int*   ei   = (const int*)  d_in[1];
    const float* ed   = (const float*)d_in[2];
    const float* wig  = (const float*)d_in[3];
    const float* semb = (const float*)d_in[4];
    const float* temb = (const float*)d_in[5];
    const float* W1   = (const float*)d_in[6];
    const float* b1   = (const float*)d_in[7];
    const float* g1   = (const float*)d_in[8];
    const float* be1  = (const float*)d_in[9];
    const float* W2   = (const float*)d_in[10];
    const float* b2   = (const float*)d_in[11];
    const float* g2   = (const float*)d_in[12];
    const float* be2  = (const float*)d_in[13];
    const float* W3   = (const float*)d_in[14];
    const float* b3   = (const float*)d_in[15];
    float* out = (float*)d_out;

    uintptr_t p = (uintptr_t)d_ws;
    #define ALLOC(ptr, type, count) \
        p = (p + 15) & ~(uintptr_t)15; type* ptr = (type*)p; p += sizeof(type) * (count)
    ALLOC(y3,     ushort_t, (size_t)E_EDGES * W3OUT);
    ALLOC(cnt,    int,      N_NODES);
    ALLOC(offs,   int,      N_NODES + 1);
    ALLOC(cursor, int,      N_NODES);
    ALLOC(eids,   int,      E_EDGES);
    ALLOC(sW1,    float,    NELEM * HD);
    ALLOC(tW1,    float,    NELEM * HD);
    ALLOC(W1T,    ushort_t, 64 * 128);
    ALLOC(W2T,    ushort_t, 64 * 64);
    ALLOC(W3T,    ushort_t, 224 * 64);
    #undef ALLOC
    if (p - (uintptr_t)d_ws > ws_size) return;

    k_prep<<<56, 256, 0, stream>>>(semb, temb, W1, W2, W3,
                                   sW1, tW1, W1T, W2T, W3T, cnt);
    k_mlp<<<E_EDGES / 64, 256, 0, stream>>>(an, ei, ed, sW1, tW1,
                                            W1T, W2T, W3T,
                                            b1, g1, be1, b2, g2, be2,
                                            b3, y3);
    k_count<<<(E_EDGES + 255) / 256, 256, 0, stream>>>(ei, cnt);
    k_scan<<<1, 1024, 0, stream>>>(cnt, offs, cursor);
    k_scatter<<<(E_EDGES + 255) / 256, 256, 0, stream>>>(ei, cursor, eids);
    k_out<<<N_NODES / 4, 256, 0, stream>>>(wig, y3, offs, eids, out);
}

// Round 14
// 259.476 us; speedup vs baseline: 3.1032x; 1.0232x over previous
//
#include <hip/hip_runtime.h>
#include <hip/hip_bf16.h>
#include <stdint.h>

#define E_EDGES 80000
#define N_NODES 10000
#define HD      64
#define DDIST   128
#define NCOEF   49
#define W3OUT   224   // M0(7) * C_SPH(32)
#define WROW    2401  // 49*49
#define NELEM   90

typedef float  f32x4  __attribute__((ext_vector_type(4)));
typedef short  bf16x8 __attribute__((ext_vector_type(8)));
typedef unsigned int  uint_t;
typedef unsigned short ushort_t;

__device__ __forceinline__ ushort_t f2b(float f) {
    uint_t u = __builtin_bit_cast(uint_t, f);
    return (ushort_t)((u + 0x7FFFu + ((u >> 16) & 1u)) >> 16);   // RNE
}
__device__ __forceinline__ uint_t pack2(float a, float b) {
    return (uint_t)f2b(a) | ((uint_t)f2b(b) << 16);
}
__device__ __forceinline__ float b2f(uint_t v) {
    return __builtin_bit_cast(float, v << 16);
}

// ---------------------------------------------------------------------------
// k_prep: fold tables (f32), W1/W2/W3 -> bf16 transposed [n][k]; zero cnt.
// ---------------------------------------------------------------------------
__global__ __launch_bounds__(256) void k_prep(
    const float* __restrict__ semb, const float* __restrict__ temb,
    const float* __restrict__ W1, const float* __restrict__ W2,
    const float* __restrict__ W3,
    float* __restrict__ sW1, float* __restrict__ tW1,
    ushort_t* __restrict__ W1T, ushort_t* __restrict__ W2T,
    ushort_t* __restrict__ W3T, int* __restrict__ cnt)
{
    const int gid = blockIdx.x * 256 + threadIdx.x;
    if (gid < NELEM * 64) {
        const int z = gid >> 6, n = gid & 63;
        float sa = 0.f, ta = 0.f;
        #pragma unroll 4
        for (int k = 0; k < 64; k++) {
            sa = fmaf(semb[z * 64 + k], W1[(128 + k) * 64 + n], sa);
            ta = fmaf(temb[z * 64 + k], W1[(192 + k) * 64 + n], ta);
        }
        sW1[z * 64 + n] = sa;
        tW1[z * 64 + n] = ta;
    }
    if (gid < 8192)  { const int n = gid >> 7, k = gid & 127; W1T[gid] = f2b(W1[k * 64 + n]); }
    if (gid < 4096)  { const int n = gid >> 6, k = gid & 63;  W2T[gid] = f2b(W2[k * 64 + n]); }
    if (gid < 14336) { const int n = gid >> 6, k = gid & 63;  W3T[gid] = f2b(W3[k * W3OUT + n]); }
    if (gid < N_NODES) cnt[gid] = 0;
}

// ---------------------------------------------------------------------------
// k_mlp (round 14): r13 MFMA version with
//  * Hs/H2s OVERLAID into Xs (wave-private 16-row quarters -> hazard-free):
//    LDS 48 KB -> 32 KB -> 4 blocks/CU (launch_bounds(256,4)).
//  * k_count folded in (one atomicAdd per edge from tid<64).
// ---------------------------------------------------------------------------
__global__ __launch_bounds__(256, 4) void k_mlp(
    const int* __restrict__ an, const int* __restrict__ ei,
    const float* __restrict__ ed,
    const float* __restrict__ sW1, const float* __restrict__ tW1,
    const ushort_t* __restrict__ W1T, const ushort_t* __restrict__ W2T,
    const ushort_t* __restrict__ W3T,
    const float* __restrict__ b1, const float* __restrict__ g1,
    const float* __restrict__ be1,
    const float* __restrict__ b2, const float* __restrict__ g2,
    const float* __restrict__ be2,
    const float* __restrict__ b3, ushort_t* __restrict__ y3,
    int* __restrict__ cnt)
{
    // XHs: during GEMM1 = Xs[64][128]; afterwards wave w's quarter
    // (ushorts [w*2048,(w+1)*2048)) holds Hs rows (first 1024) + H2s rows.
    __shared__ __align__(16) ushort_t XHs[64 * 128];  // 16 KB
    __shared__ __align__(16) ushort_t Ws[64 * 128];   // 16 KB

    const int tid  = threadIdx.x;
    const int wave = tid >> 6, lane = tid & 63;
    const int e0   = blockIdx.x * 64;
    const int mo   = wave * 16;
    const int cl   = lane & 15;
    const int kgr  = lane >> 4;

    // CSR degree count (cnt zeroed by k_prep; k_count kernel eliminated)
    if (tid < 64) atomicAdd(&cnt[ei[E_EDGES + e0 + tid]], 1);

    // ---- stage X (wave-private rows): ed f32 -> bf16 swizzled ----------------
    {
        const int m = tid >> 2, q = tid & 3;
        const float4* ed4 = (const float4*)(ed + (size_t)(e0 + m) * DDIST);
        #pragma unroll
        for (int j = 0; j < 4; j++) {
            const int kb = q * 4 + j;
            const float4 f0 = ed4[kb * 2];
            const float4 f1 = ed4[kb * 2 + 1];
            uint4 p;
            p.x = pack2(f0.x, f0.y); p.y = pack2(f0.z, f0.w);
            p.z = pack2(f1.x, f1.y); p.w = pack2(f1.z, f1.w);
            *(uint4*)&XHs[m * 128 + ((kb ^ (m & 15)) * 8)] = p;
        }
    }
    // ---- stage W1T ------------------------------------------------------------
    {
        const uint4* src = (const uint4*)W1T;
        #pragma unroll
        for (int i = 0; i < 4; i++) {
            const int B = tid + i * 256;
            const int n = B >> 4, kb = B & 15;
            *(uint4*)&Ws[n * 128 + ((kb ^ (n & 15)) * 8)] = src[B];
        }
    }

    f32x4 acc[4];
    {
        const int er0 = e0 + mo + kgr * 4;
        const int4 s4 = *(const int4*)&ei[er0];
        const int4 t4 = *(const int4*)&ei[E_EDGES + er0];
        const int zs0 = an[s4.x], zs1 = an[s4.y], zs2 = an[s4.z], zs3 = an[s4.w];
        const int zt0 = an[t4.x], zt1 = an[t4.y], zt2 = an[t4.z], zt3 = an[t4.w];
        #pragma unroll
        for (int nf = 0; nf < 4; nf++) {
            const int col = nf * 16 + cl;
            acc[nf][0] = sW1[zs0 * 64 + col] + tW1[zt0 * 64 + col];
            acc[nf][1] = sW1[zs1 * 64 + col] + tW1[zt1 * 64 + col];
            acc[nf][2] = sW1[zs2 * 64 + col] + tW1[zt2 * 64 + col];
            acc[nf][3] = sW1[zs3 * 64 + col] + tW1[zt3 * 64 + col];
        }
    }
    __syncthreads();

    // ---- GEMM1: K=128 ----------------------------------------------------------
    {
        const int m = mo + cl;
        #pragma unroll
        for (int kc = 0; kc < 4; kc++) {
            const int kb = kc * 4 + kgr;
            const bf16x8 a = *(const bf16x8*)&XHs[m * 128 + ((kb ^ (m & 15)) * 8)];
            #pragma unroll
            for (int nf = 0; nf < 4; nf++) {
                const int n = nf * 16 + cl;
                const bf16x8 b = *(const bf16x8*)&Ws[n * 128 + ((kb ^ (n & 15)) * 8)];
                acc[nf] = __builtin_amdgcn_mfma_f32_16x16x32_bf16(a, b, acc[nf], 0, 0, 0);
            }
        }
    }

    // ---- LN1 + silu -> H rows (overlay: own wave's quarter) --------------------
    {
        float b1v[4], g1v[4], e1v[4];
        #pragma unroll
        for (int nf = 0; nf < 4; nf++) {
            b1v[nf] = b1[nf * 16 + cl];
            g1v[nf] = g1[nf * 16 + cl];
            e1v[nf] = be1[nf * 16 + cl];
        }
        #pragma unroll
        for (int nf = 0; nf < 4; nf++)
            #pragma unroll
            for (int r = 0; r < 4; r++) acc[nf][r] += b1v[nf];
        #pragma unroll
        for (int r = 0; r < 4; r++) {
            float s = acc[0][r] + acc[1][r] + acc[2][r] + acc[3][r];
            float q = acc[0][r]*acc[0][r] + acc[1][r]*acc[1][r]
                    + acc[2][r]*acc[2][r] + acc[3][r]*acc[3][r];
            s += __shfl_xor(s, 1, 64); q += __shfl_xor(q, 1, 64);
            s += __shfl_xor(s, 2, 64); q += __shfl_xor(q, 2, 64);
            s += __shfl_xor(s, 4, 64); q += __shfl_xor(q, 4, 64);
            s += __shfl_xor(s, 8, 64); q += __shfl_xor(q, 8, 64);
            const float mu  = s * (1.f / 64.f);
            const float var = fmaxf(q * (1.f / 64.f) - mu * mu, 0.f);
            const float rstd = rsqrtf(var + 1e-5f);
            const int m_h = mo + kgr * 4 + r;
            #pragma unroll
            for (int nf = 0; nf < 4; nf++) {
                const float t = (acc[nf][r] - mu) * rstd * g1v[nf] + e1v[nf];
                const float h = t / (1.f + expf(-t));
                const int ch = nf * 16 + cl;
                XHs[wave * 2048 + (m_h & 15) * 64 +
                    (((ch >> 3) ^ (m_h & 7)) * 8) + (ch & 7)] = f2b(h);
            }
        }
    }
    __syncthreads();

    // ---- stage W2T --------------------------------------------------------------
    {
        const uint4* src = (const uint4*)W2T;
        #pragma unroll
        for (int i = 0; i < 2; i++) {
            const int B = tid + i * 256;
            const int n = B >> 3, kb = B & 7;
            *(uint4*)&Ws[n * 64 + ((kb ^ (n & 7)) * 8)] = src[B];
        }
    }
    __syncthreads();

    // ---- GEMM2: K=64 ------------------------------------------------------------
    f32x4 acc2[4];
    {
        const f32x4 z = {0.f, 0.f, 0.f, 0.f};
        acc2[0] = z; acc2[1] = z; acc2[2] = z; acc2[3] = z;
        #pragma unroll
        for (int kc = 0; kc < 2; kc++) {
            const int kb = kc * 4 + kgr;
            const bf16x8 a = *(const bf16x8*)&XHs[wave * 2048 + cl * 64 +
                                                 ((kb ^ ((mo + cl) & 7)) * 8)];
            #pragma unroll
            for (int nf = 0; nf < 4; nf++) {
                const int n = nf * 16 + cl;
                const bf16x8 b = *(const bf16x8*)&Ws[n * 64 + ((kb ^ (n & 7)) * 8)];
                acc2[nf] = __builtin_amdgcn_mfma_f32_16x16x32_bf16(a, b, acc2[nf], 0, 0, 0);
            }
        }
    }

    // ---- LN2 + silu -> H2 rows (overlay, own quarter + 1024) ---------------------
    {
        float b2v[4], g2v[4], e2v[4];
        #pragma unroll
        for (int nf = 0; nf < 4; nf++) {
            b2v[nf] = b2[nf * 16 + cl];
            g2v[nf] = g2[nf * 16 + cl];
            e2v[nf] = be2[nf * 16 + cl];
        }
        #pragma unroll
        for (int nf = 0; nf < 4; nf++)
            #pragma unroll
            for (int r = 0; r < 4; r++) acc2[nf][r] += b2v[nf];
        #pragma unroll
        for (int r = 0; r < 4; r++) {
            float s = acc2[0][r] + acc2[1][r] + acc2[2][r] + acc2[3][r];
            float q = acc2[0][r]*acc2[0][r] + acc2[1][r]*acc2[1][r]
                    + acc2[2][r]*acc2[2][r] + acc2[3][r]*acc2[3][r];
            s += __shfl_xor(s, 1, 64); q += __shfl_xor(q, 1, 64);
            s += __shfl_xor(s, 2, 64); q += __shfl_xor(q, 2, 64);
            s += __shfl_xor(s, 4, 64); q += __shfl_xor(q, 4, 64);
            s += __shfl_xor(s, 8, 64); q += __shfl_xor(q, 8, 64);
            const float mu  = s * (1.f / 64.f);
            const float var = fmaxf(q * (1.f / 64.f) - mu * mu, 0.f);
            const float rstd = rsqrtf(var + 1e-5f);
            const int m_h = mo + kgr * 4 + r;
            #pragma unroll
            for (int nf = 0; nf < 4; nf++) {
                const float t = (acc2[nf][r] - mu) * rstd * g2v[nf] + e2v[nf];
                const float h = t / (1.f + expf(-t));
                const int ch = nf * 16 + cl;
                XHs[wave * 2048 + 1024 + (m_h & 15) * 64 +
                    (((ch >> 3) ^ (m_h & 7)) * 8) + (ch & 7)] = f2b(h);
            }
        }
    }
    __syncthreads();

    // ---- GEMM3 in two N=112 halves through Ws -------------------------------------
    const int er0 = e0 + mo + kgr * 4;
    #pragma unroll
    for (int half = 0; half < 2; half++) {
        {
            const uint4* src = (const uint4*)W3T;
            #pragma unroll
            for (int i = 0; i < 4; i++) {
                const int B = tid + i * 256;
                if (B < 896) {
                    const int nn = B >> 3, kb = B & 7;
                    *(uint4*)&Ws[nn * 64 + ((kb ^ (nn & 7)) * 8)] = src[half * 896 + B];
                }
            }
        }
        __syncthreads();

        f32x4 acc3[7];
        {
            const f32x4 z = {0.f, 0.f, 0.f, 0.f};
            #pragma unroll
            for (int nf = 0; nf < 7; nf++) acc3[nf] = z;
        }
        #pragma unroll
        for (int kc = 0; kc < 2; kc++) {
            const int kb = kc * 4 + kgr;
            const bf16x8 a = *(const bf16x8*)&XHs[wave * 2048 + 1024 + cl * 64 +
                                                 ((kb ^ ((mo + cl) & 7)) * 8)];
            #pragma unroll
            for (int nf = 0; nf < 7; nf++) {
                const int nn = nf * 16 + cl;
                const bf16x8 b = *(const bf16x8*)&Ws[nn * 64 + ((kb ^ (nn & 7)) * 8)];
                acc3[nf] = __builtin_amdgcn_mfma_f32_16x16x32_bf16(a, b, acc3[nf], 0, 0, 0);
            }
        }
        #pragma unroll
        for (int nf = 0; nf < 7; nf++) {
            const int ch = half * 112 + nf * 16 + cl;
            const float bv = b3[ch];
            #pragma unroll
            for (int r = 0; r < 4; r++)
                y3[(size_t)(er0 + r) * W3OUT + ch] =
                    f2b((acc3[nf][r] + bv) * (1.0f / 5.862f));
        }
        __syncthreads();
    }
}

// ---------------------------------------------------------------------------
// CSR scan + scatter (k_count folded into k_mlp)
// ---------------------------------------------------------------------------
__global__ __launch_bounds__(1024) void k_scan(const int* __restrict__ cnt,
                                               int* __restrict__ offs,
                                               int* __restrict__ cursor) {
    __shared__ int wsum[16];
    __shared__ int carry_s;
    const int tid  = threadIdx.x;
    const int lane = tid & 63;
    const int wid  = tid >> 6;
    if (tid == 0) carry_s = 0;
    __syncthreads();
    for (int base = 0; base < N_NODES; base += 1024) {
        const int idx = base + tid;
        const int v = (idx < N_NODES) ? cnt[idx] : 0;
        int s = v;
        #pragma unroll
        for (int off = 1; off < 64; off <<= 1) {
            const int t = __shfl_up(s, off, 64);
            if (lane >= off) s += t;
        }
        if (lane == 63) wsum[wid] = s;
        __syncthreads();
        if (wid == 0) {
            const int t = (lane < 16) ? wsum[lane] : 0;
            int ss = t;
            #pragma unroll
            for (int off = 1; off < 16; off <<= 1) {
                const int u = __shfl_up(ss, off, 64);
                if (lane >= off) ss += u;
            }
            if (lane < 16) wsum[lane] = ss - t;
        }
        __syncthreads();
        const int carry = carry_s;
        const int excl = carry + wsum[wid] + s - v;
        if (idx < N_NODES) { offs[idx] = excl; cursor[idx] = excl; }
        __syncthreads();
        if (tid == 1023) carry_s = carry + wsum[15] + s;
    }
    __syncthreads();
    if (tid == 0) offs[N_NODES] = carry_s;
}

__global__ void k_scatter(const int* __restrict__ ei, int* __restrict__ cursor,
                          int* __restrict__ eids) {
    const int e = blockIdx.x * 256 + threadIdx.x;
    if (e < E_EDGES) {
        const int pos = atomicAdd(&cursor[ei[E_EDGES + e]], 1);
        eids[pos] = e;
    }
}

// ---------------------------------------------------------------------------
// k_out (FROZEN from round 13): wave per node, barrier-free, depth-2
// pipeline, bf16 y3.
// ---------------------------------------------------------------------------
__global__ __launch_bounds__(256) void k_out(
    const float* __restrict__ wig, const ushort_t* __restrict__ y3,
    const int* __restrict__ offs, const int* __restrict__ eids,
    float* __restrict__ out)
{
    __shared__ __align__(16) float wl[4][2][400];
    __shared__ __align__(16) float yl[4][2][224];
    const int tid  = threadIdx.x;
    const int wave = tid >> 6;
    const int lane = tid & 63;
    const int n    = blockIdx.x * 4 + wave;
    const int c    = lane & 31;
    const int h    = lane >> 5;
    const int beg  = offs[n];
    const int end  = offs[n + 1];

    float acc[25];
    #pragma unroll
    for (int r = 0; r < 25; r++) acc[r] = 0.f;

    float gvA[6], gvB[6];
    uint2 yvA, yvB;

    #define GATHER(S, E) do {                                               \
        const float* __restrict__ wb_ = wig + (size_t)(E) * WROW;           \
        _Pragma("unroll")                                                   \
        for (int g = 0; g < 6; g++) {                                       \
            const int t = lane + 64 * g;                                    \
            if (t < 343) {                                                  \
                const int row = t / 7;                                      \
                const int l   = t - row * 7;                                \
                gv##S[g] = wb_[row * 49 + l * l + l];                       \
            }                                                               \
        }                                                                   \
        if (lane < 56)                                                      \
            yv##S = ((const uint2*)(y3 + (size_t)(E) * W3OUT))[lane];       \
    } while (0)

    #define COMMIT(S, B) do {                                               \
        _Pragma("unroll")                                                   \
        for (int g = 0; g < 6; g++) {                                       \
            const int t = lane + 64 * g;                                    \
            if (t < 343) {                                                  \
                const int row = t / 7;                                      \
                const int l   = t - row * 7;                                \
                wl[wave][B][row * 8 + l] = gv##S[g];                        \
            }                                                               \
        }                                                                   \
        if (lane < 56) {                                                    \
            float4 yf;                                                      \
            yf.x = b2f(yv##S.x & 0xffffu);                                  \
            yf.y = b2f(yv##S.x >> 16);                                      \
            yf.z = b2f(yv##S.y & 0xffffu);                                  \
            yf.w = b2f(yv##S.y >> 16);                                      \
            ((float4*)yl[wave][B])[lane] = yf;                              \
        }                                                                   \
    } while (0)

    #define FENCE() do {                                                    \
        asm volatile("s_waitcnt lgkmcnt(0)" ::: "memory");                  \
        __builtin_amdgcn_sched_barrier(0);                                  \
    } while (0)

    #define COMPUTE(B) do {                                                 \
        float yr[7];                                                        \
        _Pragma("unroll")                                                   \
        for (int l = 0; l < 7; l++) yr[l] = yl[wave][B][l * 32 + c];        \
        _Pragma("unroll")                                                   \
        for (int r = 0; r < 25; r++) {                                      \
            const int i = 2 * r + h;                                        \
            if (i < NCOEF) {                                                \
                const float4 wa = *(const float4*)(&wl[wave][B][i * 8]);    \
                const float4 wb = *(const float4*)(&wl[wave][B][i * 8 + 4]);\
                acc[r] += wa.x * yr[0] + wa.y * yr[1] + wa.z * yr[2]        \
                        + wa.w * yr[3] + wb.x * yr[4] + wb.y * yr[5]        \
                        + wb.z * yr[6];                                     \
            }                                                               \
        }                                                                   \
    } while (0)

    if (beg < end)     GATHER(A, eids[beg]);
    if (beg + 1 < end) GATHER(B, eids[beg + 1]);
    if (beg < end)     COMMIT(A, 0);

    for (int ie = beg; ie < end; ie += 2) {
        if (ie + 2 < end) GATHER(A, eids[ie + 2]);
        FENCE();
        COMPUTE(0);
        if (ie + 1 < end) COMMIT(B, 1);
        if (ie + 1 < end) {
            if (ie + 3 < end) GATHER(B, eids[ie + 3]);
            FENCE();
            COMPUTE(1);
            if (ie + 2 < end) COMMIT(A, 0);
        }
    }

    #pragma unroll
    for (int r = 0; r < 25; r++) {
        const int i = 2 * r + h;
        if (i < NCOEF)
            out[(size_t)n * (NCOEF * 32) + i * 32 + c] = acc[r];
    }
}

// ---------------------------------------------------------------------------
extern "C" void kernel_launch(void* const* d_in, const int* in_sizes, int n_in,
                              void* d_out, int out_size, void* d_ws, size_t ws_size,
                              hipStream_t stream)
{
    const int*   an   = (const int*)  d_in[0];
    const int*   ei   = (const int*)  d_in[1];
    const float* ed   = (const float*)d_in[2];
    const float* wig  = (const float*)d_in[3];
    const float* semb = (const float*)d_in[4];
    const float* temb = (const float*)d_in[5];
    const float* W1   = (const float*)d_in[6];
    const float* b1   = (const float*)d_in[7];
    const float* g1   = (const float*)d_in[8];
    const float* be1  = (const float*)d_in[9];
    const float* W2   = (const float*)d_in[10];
    const float* b2   = (const float*)d_in[11];
    const float* g2   = (const float*)d_in[12];
    const float* be2  = (const float*)d_in[13];
    const float* W3   = (const float*)d_in[14];
    const float* b3   = (const float*)d_in[15];
    float* out = (float*)d_out;

    uintptr_t p = (uintptr_t)d_ws;
    #define ALLOC(ptr, type, count) \
        p = (p + 15) & ~(uintptr_t)15; type* ptr = (type*)p; p += sizeof(type) * (count)
    ALLOC(y3,     ushort_t, (size_t)E_EDGES * W3OUT);
    ALLOC(cnt,    int,      N_NODES);
    ALLOC(offs,   int,      N_NODES + 1);
    ALLOC(cursor, int,      N_NODES);
    ALLOC(eids,   int,      E_EDGES);
    ALLOC(sW1,    float,    NELEM * HD);
    ALLOC(tW1,    float,    NELEM * HD);
    ALLOC(W1T,    ushort_t, 64 * 128);
    ALLOC(W2T,    ushort_t, 64 * 64);
    ALLOC(W3T,    ushort_t, 224 * 64);
    #undef ALLOC
    if (p - (uintptr_t)d_ws > ws_size) return;

    k_prep<<<56, 256, 0, stream>>>(semb, temb, W1, W2, W3,
                                   sW1, tW1, W1T, W2T, W3T, cnt);
    k_mlp<<<E_EDGES / 64, 256, 0, stream>>>(an, ei, ed, sW1, tW1,
                                            W1T, W2T, W3T,
                                            b1, g1, be1, b2, g2, be2,
                                            b3, y3, cnt);
    k_scan<<<1, 1024, 0, stream>>>(cnt, offs, cursor);
    k_scatter<<<(E_EDGES + 255) / 256, 256, 0, stream>>>(ei, cursor, eids);
    k_out<<<N_NODES / 4, 256, 0, stream>>>(wig, y3, offs, eids, out);
}

// Round 15
// 257.893 us; speedup vs baseline: 3.1223x; 1.0061x over previous
//
#include <hip/hip_runtime.h>
#include <hip/hip_bf16.h>
#include <stdint.h>

#define E_EDGES 80000
#define N_NODES 10000
#define HD      64
#define DDIST   128
#define NCOEF   49
#define W3OUT   224   // M0(7) * C_SPH(32)
#define WROW    2401  // 49*49
#define NELEM   90

typedef float  f32x4  __attribute__((ext_vector_type(4)));
typedef short  bf16x8 __attribute__((ext_vector_type(8)));
typedef unsigned int  uint_t;
typedef unsigned short ushort_t;

__device__ __forceinline__ ushort_t f2b(float f) {
    uint_t u = __builtin_bit_cast(uint_t, f);
    return (ushort_t)((u + 0x7FFFu + ((u >> 16) & 1u)) >> 16);   // RNE
}
__device__ __forceinline__ uint_t pack2(float a, float b) {
    return (uint_t)f2b(a) | ((uint_t)f2b(b) << 16);
}
__device__ __forceinline__ float b2f(uint_t v) {
    return __builtin_bit_cast(float, v << 16);
}

// ---------------------------------------------------------------------------
// k_prep: fold tables (f32), W1/W2/W3 -> bf16 transposed [n][k]; zero cnt.
// ---------------------------------------------------------------------------
__global__ __launch_bounds__(256) void k_prep(
    const float* __restrict__ semb, const float* __restrict__ temb,
    const float* __restrict__ W1, const float* __restrict__ W2,
    const float* __restrict__ W3,
    float* __restrict__ sW1, float* __restrict__ tW1,
    ushort_t* __restrict__ W1T, ushort_t* __restrict__ W2T,
    ushort_t* __restrict__ W3T, int* __restrict__ cnt)
{
    const int gid = blockIdx.x * 256 + threadIdx.x;
    if (gid < NELEM * 64) {
        const int z = gid >> 6, n = gid & 63;
        float sa = 0.f, ta = 0.f;
        #pragma unroll 4
        for (int k = 0; k < 64; k++) {
            sa = fmaf(semb[z * 64 + k], W1[(128 + k) * 64 + n], sa);
            ta = fmaf(temb[z * 64 + k], W1[(192 + k) * 64 + n], ta);
        }
        sW1[z * 64 + n] = sa;
        tW1[z * 64 + n] = ta;
    }
    if (gid < 8192)  { const int n = gid >> 7, k = gid & 127; W1T[gid] = f2b(W1[k * 64 + n]); }
    if (gid < 4096)  { const int n = gid >> 6, k = gid & 63;  W2T[gid] = f2b(W2[k * 64 + n]); }
    if (gid < 14336) { const int n = gid >> 6, k = gid & 63;  W3T[gid] = f2b(W3[k * W3OUT + n]); }
    if (gid < N_NODES) cnt[gid] = 0;
}

// ---------------------------------------------------------------------------
// k_mlp (round 15): r14 overlay version with
//  * W2 in its own LDS buffer, staged at kernel start (LDS 40 KB, 4 blk/CU)
//  * barriers 8 -> 5: LN1->GEMM2 and LN2->(sync moved) rely on wave-private
//    H/H2 rows + compiler lgkmcnt on the may-aliasing XHs array.
// ---------------------------------------------------------------------------
__global__ __launch_bounds__(256, 4) void k_mlp(
    const int* __restrict__ an, const int* __restrict__ ei,
    const float* __restrict__ ed,
    const float* __restrict__ sW1, const float* __restrict__ tW1,
    const ushort_t* __restrict__ W1T, const ushort_t* __restrict__ W2T,
    const ushort_t* __restrict__ W3T,
    const float* __restrict__ b1, const float* __restrict__ g1,
    const float* __restrict__ be1,
    const float* __restrict__ b2, const float* __restrict__ g2,
    const float* __restrict__ be2,
    const float* __restrict__ b3, ushort_t* __restrict__ y3,
    int* __restrict__ cnt)
{
    __shared__ __align__(16) ushort_t XHs[64 * 128];  // 16 KB (X, then H/H2 overlay)
    __shared__ __align__(16) ushort_t Ws[64 * 128];   // 16 KB (W1T, then W3T halves)
    __shared__ __align__(16) ushort_t Ws2[64 * 64];   // 8 KB  (W2T, staged once)

    const int tid  = threadIdx.x;
    const int wave = tid >> 6, lane = tid & 63;
    const int e0   = blockIdx.x * 64;
    const int mo   = wave * 16;
    const int cl   = lane & 15;
    const int kgr  = lane >> 4;

    // CSR degree count (cnt zeroed by k_prep)
    if (tid < 64) atomicAdd(&cnt[ei[E_EDGES + e0 + tid]], 1);

    // ---- stage X (wave-private rows): ed f32 -> bf16 swizzled ----------------
    {
        const int m = tid >> 2, q = tid & 3;
        const float4* ed4 = (const float4*)(ed + (size_t)(e0 + m) * DDIST);
        #pragma unroll
        for (int j = 0; j < 4; j++) {
            const int kb = q * 4 + j;
            const float4 f0 = ed4[kb * 2];
            const float4 f1 = ed4[kb * 2 + 1];
            uint4 p;
            p.x = pack2(f0.x, f0.y); p.y = pack2(f0.z, f0.w);
            p.z = pack2(f1.x, f1.y); p.w = pack2(f1.z, f1.w);
            *(uint4*)&XHs[m * 128 + ((kb ^ (m & 15)) * 8)] = p;
        }
    }
    // ---- stage W1T + W2T (both before the single pre-GEMM barrier) -----------
    {
        const uint4* src = (const uint4*)W1T;
        #pragma unroll
        for (int i = 0; i < 4; i++) {
            const int B = tid + i * 256;
            const int n = B >> 4, kb = B & 15;
            *(uint4*)&Ws[n * 128 + ((kb ^ (n & 15)) * 8)] = src[B];
        }
        const uint4* src2 = (const uint4*)W2T;
        #pragma unroll
        for (int i = 0; i < 2; i++) {
            const int B = tid + i * 256;
            const int n = B >> 3, kb = B & 7;
            *(uint4*)&Ws2[n * 64 + ((kb ^ (n & 7)) * 8)] = src2[B];
        }
    }

    f32x4 acc[4];
    {
        const int er0 = e0 + mo + kgr * 4;
        const int4 s4 = *(const int4*)&ei[er0];
        const int4 t4 = *(const int4*)&ei[E_EDGES + er0];
        const int zs0 = an[s4.x], zs1 = an[s4.y], zs2 = an[s4.z], zs3 = an[s4.w];
        const int zt0 = an[t4.x], zt1 = an[t4.y], zt2 = an[t4.z], zt3 = an[t4.w];
        #pragma unroll
        for (int nf = 0; nf < 4; nf++) {
            const int col = nf * 16 + cl;
            acc[nf][0] = sW1[zs0 * 64 + col] + tW1[zt0 * 64 + col];
            acc[nf][1] = sW1[zs1 * 64 + col] + tW1[zt1 * 64 + col];
            acc[nf][2] = sW1[zs2 * 64 + col] + tW1[zt2 * 64 + col];
            acc[nf][3] = sW1[zs3 * 64 + col] + tW1[zt3 * 64 + col];
        }
    }
    __syncthreads();   // barrier 1: X, W1, W2 staged

    // ---- GEMM1: K=128 ----------------------------------------------------------
    {
        const int m = mo + cl;
        #pragma unroll
        for (int kc = 0; kc < 4; kc++) {
            const int kb = kc * 4 + kgr;
            const bf16x8 a = *(const bf16x8*)&XHs[m * 128 + ((kb ^ (m & 15)) * 8)];
            #pragma unroll
            for (int nf = 0; nf < 4; nf++) {
                const int n = nf * 16 + cl;
                const bf16x8 b = *(const bf16x8*)&Ws[n * 128 + ((kb ^ (n & 15)) * 8)];
                acc[nf] = __builtin_amdgcn_mfma_f32_16x16x32_bf16(a, b, acc[nf], 0, 0, 0);
            }
        }
    }

    // ---- LN1 + silu -> H rows (wave-private quarter; no barrier needed) --------
    {
        float b1v[4], g1v[4], e1v[4];
        #pragma unroll
        for (int nf = 0; nf < 4; nf++) {
            b1v[nf] = b1[nf * 16 + cl];
            g1v[nf] = g1[nf * 16 + cl];
            e1v[nf] = be1[nf * 16 + cl];
        }
        #pragma unroll
        for (int nf = 0; nf < 4; nf++)
            #pragma unroll
            for (int r = 0; r < 4; r++) acc[nf][r] += b1v[nf];
        #pragma unroll
        for (int r = 0; r < 4; r++) {
            float s = acc[0][r] + acc[1][r] + acc[2][r] + acc[3][r];
            float q = acc[0][r]*acc[0][r] + acc[1][r]*acc[1][r]
                    + acc[2][r]*acc[2][r] + acc[3][r]*acc[3][r];
            s += __shfl_xor(s, 1, 64); q += __shfl_xor(q, 1, 64);
            s += __shfl_xor(s, 2, 64); q += __shfl_xor(q, 2, 64);
            s += __shfl_xor(s, 4, 64); q += __shfl_xor(q, 4, 64);
            s += __shfl_xor(s, 8, 64); q += __shfl_xor(q, 8, 64);
            const float mu  = s * (1.f / 64.f);
            const float var = fmaxf(q * (1.f / 64.f) - mu * mu, 0.f);
            const float rstd = rsqrtf(var + 1e-5f);
            const int m_h = mo + kgr * 4 + r;
            #pragma unroll
            for (int nf = 0; nf < 4; nf++) {
                const float t = (acc[nf][r] - mu) * rstd * g1v[nf] + e1v[nf];
                const float h = t / (1.f + expf(-t));
                const int ch = nf * 16 + cl;
                XHs[wave * 2048 + (m_h & 15) * 64 +
                    (((ch >> 3) ^ (m_h & 7)) * 8) + (ch & 7)] = f2b(h);
            }
        }
    }

    // ---- GEMM2: K=64 (W2 pre-staged; H rows wave-private) ----------------------
    f32x4 acc2[4];
    {
        const f32x4 z = {0.f, 0.f, 0.f, 0.f};
        acc2[0] = z; acc2[1] = z; acc2[2] = z; acc2[3] = z;
        #pragma unroll
        for (int kc = 0; kc < 2; kc++) {
            const int kb = kc * 4 + kgr;
            const bf16x8 a = *(const bf16x8*)&XHs[wave * 2048 + cl * 64 +
                                                 ((kb ^ ((mo + cl) & 7)) * 8)];
            #pragma unroll
            for (int nf = 0; nf < 4; nf++) {
                const int n = nf * 16 + cl;
                const bf16x8 b = *(const bf16x8*)&Ws2[n * 64 + ((kb ^ (n & 7)) * 8)];
                acc2[nf] = __builtin_amdgcn_mfma_f32_16x16x32_bf16(a, b, acc2[nf], 0, 0, 0);
            }
        }
    }

    // ---- LN2 + silu -> H2 rows (wave-private; no barrier) ----------------------
    {
        float b2v[4], g2v[4], e2v[4];
        #pragma unroll
        for (int nf = 0; nf < 4; nf++) {
            b2v[nf] = b2[nf * 16 + cl];
            g2v[nf] = g2[nf * 16 + cl];
            e2v[nf] = be2[nf * 16 + cl];
        }
        #pragma unroll
        for (int nf = 0; nf < 4; nf++)
            #pragma unroll
            for (int r = 0; r < 4; r++) acc2[nf][r] += b2v[nf];
        #pragma unroll
        for (int r = 0; r < 4; r++) {
            float s = acc2[0][r] + acc2[1][r] + acc2[2][r] + acc2[3][r];
            float q = acc2[0][r]*acc2[0][r] + acc2[1][r]*acc2[1][r]
                    + acc2[2][r]*acc2[2][r] + acc2[3][r]*acc2[3][r];
            s += __shfl_xor(s, 1, 64); q += __shfl_xor(q, 1, 64);
            s += __shfl_xor(s, 2, 64); q += __shfl_xor(q, 2, 64);
            s += __shfl_xor(s, 4, 64); q += __shfl_xor(q, 4, 64);
            s += __shfl_xor(s, 8, 64); q += __shfl_xor(q, 8, 64);
            const float mu  = s * (1.f / 64.f);
            const float var = fmaxf(q * (1.f / 64.f) - mu * mu, 0.f);
            const float rstd = rsqrtf(var + 1e-5f);
            const int m_h = mo + kgr * 4 + r;
            #pragma unroll
            for (int nf = 0; nf < 4; nf++) {
                const float t = (acc2[nf][r] - mu) * rstd * g2v[nf] + e2v[nf];
                const float h = t / (1.f + expf(-t));
                const int ch = nf * 16 + cl;
                XHs[wave * 2048 + 1024 + (m_h & 15) * 64 +
                    (((ch >> 3) ^ (m_h & 7)) * 8) + (ch & 7)] = f2b(h);
            }
        }
    }
    __syncthreads();   // barrier 2: all waves past GEMM1 -> Ws reusable for W3

    // ---- GEMM3 in two N=112 halves through Ws -------------------------------------
    const int er0 = e0 + mo + kgr * 4;
    #pragma unroll
    for (int half = 0; half < 2; half++) {
        {
            const uint4* src = (const uint4*)W3T;
            #pragma unroll
            for (int i = 0; i < 4; i++) {
                const int B = tid + i * 256;
                if (B < 896) {
                    const int nn = B >> 3, kb = B & 7;
                    *(uint4*)&Ws[nn * 64 + ((kb ^ (nn & 7)) * 8)] = src[half * 896 + B];
                }
            }
        }
        __syncthreads();   // barriers 3/5: W3 half staged

        f32x4 acc3[7];
        {
            const f32x4 z = {0.f, 0.f, 0.f, 0.f};
            #pragma unroll
            for (int nf = 0; nf < 7; nf++) acc3[nf] = z;
        }
        #pragma unroll
        for (int kc = 0; kc < 2; kc++) {
            const int kb = kc * 4 + kgr;
            const bf16x8 a = *(const bf16x8*)&XHs[wave * 2048 + 1024 + cl * 64 +
                                                 ((kb ^ ((mo + cl) & 7)) * 8)];
            #pragma unroll
            for (int nf = 0; nf < 7; nf++) {
                const int nn = nf * 16 + cl;
                const bf16x8 b = *(const bf16x8*)&Ws[nn * 64 + ((kb ^ (nn & 7)) * 8)];
                acc3[nf] = __builtin_amdgcn_mfma_f32_16x16x32_bf16(a, b, acc3[nf], 0, 0, 0);
            }
        }
        #pragma unroll
        for (int nf = 0; nf < 7; nf++) {
            const int ch = half * 112 + nf * 16 + cl;
            const float bv = b3[ch];
            #pragma unroll
            for (int r = 0; r < 4; r++)
                y3[(size_t)(er0 + r) * W3OUT + ch] =
                    f2b((acc3[nf][r] + bv) * (1.0f / 5.862f));
        }
        __syncthreads();   // barrier 4: done reading Ws before next half
    }
}

// ---------------------------------------------------------------------------
// CSR scan + scatter
// ---------------------------------------------------------------------------
__global__ __launch_bounds__(1024) void k_scan(const int* __restrict__ cnt,
                                               int* __restrict__ offs,
                                               int* __restrict__ cursor) {
    __shared__ int wsum[16];
    __shared__ int carry_s;
    const int tid  = threadIdx.x;
    const int lane = tid & 63;
    const int wid  = tid >> 6;
    if (tid == 0) carry_s = 0;
    __syncthreads();
    for (int base = 0; base < N_NODES; base += 1024) {
        const int idx = base + tid;
        const int v = (idx < N_NODES) ? cnt[idx] : 0;
        int s = v;
        #pragma unroll
        for (int off = 1; off < 64; off <<= 1) {
            const int t = __shfl_up(s, off, 64);
            if (lane >= off) s += t;
        }
        if (lane == 63) wsum[wid] = s;
        __syncthreads();
        if (wid == 0) {
            const int t = (lane < 16) ? wsum[lane] : 0;
            int ss = t;
            #pragma unroll
            for (int off = 1; off < 16; off <<= 1) {
                const int u = __shfl_up(ss, off, 64);
                if (lane >= off) ss += u;
            }
            if (lane < 16) wsum[lane] = ss - t;
        }
        __syncthreads();
        const int carry = carry_s;
        const int excl = carry + wsum[wid] + s - v;
        if (idx < N_NODES) { offs[idx] = excl; cursor[idx] = excl; }
        __syncthreads();
        if (tid == 1023) carry_s = carry + wsum[15] + s;
    }
    __syncthreads();
    if (tid == 0) offs[N_NODES] = carry_s;
}

__global__ void k_scatter(const int* __restrict__ ei, int* __restrict__ cursor,
                          int* __restrict__ eids) {
    const int e = blockIdx.x * 256 + threadIdx.x;
    if (e < E_EDGES) {
        const int pos = atomicAdd(&cursor[ei[E_EDGES + e]], 1);
        eids[pos] = e;
    }
}

// ---------------------------------------------------------------------------
// k_out (round 15): wave per node, barrier-free, DEPTH-3 pipeline.
// Three named register sets (A/B/C) rotating through three LDS buffers,
// unroll-3 edge loop: each gather has ~2 edge-iterations of latency
// tolerance before its vmcnt wait.  bf16 y3.
// ---------------------------------------------------------------------------
__global__ __launch_bounds__(256) void k_out(
    const float* __restrict__ wig, const ushort_t* __restrict__ y3,
    const int* __restrict__ offs, const int* __restrict__ eids,
    float* __restrict__ out)
{
    __shared__ __align__(16) float wl[4][3][400];
    __shared__ __align__(16) float yl[4][3][224];
    const int tid  = threadIdx.x;
    const int wave = tid >> 6;
    const int lane = tid & 63;
    const int n    = blockIdx.x * 4 + wave;
    const int c    = lane & 31;
    const int h    = lane >> 5;
    const int beg  = offs[n];
    const int end  = offs[n + 1];

    float acc[25];
    #pragma unroll
    for (int r = 0; r < 25; r++) acc[r] = 0.f;

    float gvA[6], gvB[6], gvC[6];
    uint2 yvA, yvB, yvC;

    #define GATHER(S, E) do {                                               \
        const float* __restrict__ wb_ = wig + (size_t)(E) * WROW;           \
        _Pragma("unroll")                                                   \
        for (int g = 0; g < 6; g++) {                                       \
            const int t = lane + 64 * g;                                    \
            if (t < 343) {                                                  \
                const int row = t / 7;                                      \
                const int l   = t - row * 7;                                \
                gv##S[g] = wb_[row * 49 + l * l + l];                       \
            }                                                               \
        }                                                                   \
        if (lane < 56)                                                      \
            yv##S = ((const uint2*)(y3 + (size_t)(E) * W3OUT))[lane];       \
    } while (0)

    #define COMMIT(S, B) do {                                               \
        _Pragma("unroll")                                                   \
        for (int g = 0; g < 6; g++) {                                       \
            const int t = lane + 64 * g;                                    \
            if (t < 343) {                                                  \
                const int row = t / 7;                                      \
                const int l   = t - row * 7;                                \
                wl[wave][B][row * 8 + l] = gv##S[g];                        \
            }                                                               \
        }                                                                   \
        if (lane < 56) {                                                    \
            float4 yf;                                                      \
            yf.x = b2f(yv##S.x & 0xffffu);                                  \
            yf.y = b2f(yv##S.x >> 16);                                      \
            yf.z = b2f(yv##S.y & 0xffffu);                                  \
            yf.w = b2f(yv##S.y >> 16);                                      \
            ((float4*)yl[wave][B])[lane] = yf;                              \
        }                                                                   \
    } while (0)

    #define FENCE() do {                                                    \
        asm volatile("s_waitcnt lgkmcnt(0)" ::: "memory");                  \
        __builtin_amdgcn_sched_barrier(0);                                  \
    } while (0)

    #define COMPUTE(B) do {                                                 \
        float yr[7];                                                        \
        _Pragma("unroll")                                                   \
        for (int l = 0; l < 7; l++) yr[l] = yl[wave][B][l * 32 + c];        \
        _Pragma("unroll")                                                   \
        for (int r = 0; r < 25; r++) {                                      \
            const int i = 2 * r + h;                                        \
            if (i < NCOEF) {                                                \
                const float4 wa = *(const float4*)(&wl[wave][B][i * 8]);    \
                const float4 wb = *(const float4*)(&wl[wave][B][i * 8 + 4]);\
                acc[r] += wa.x * yr[0] + wa.y * yr[1] + wa.z * yr[2]        \
                        + wa.w * yr[3] + wb.x * yr[4] + wb.y * yr[5]        \
                        + wb.z * yr[6];                                     \
            }                                                               \
        }                                                                   \
    } while (0)

    if (beg < end)     GATHER(A, eids[beg]);
    if (beg + 1 < end) GATHER(B, eids[beg + 1]);
    if (beg < end)     COMMIT(A, 0);

    for (int ie = beg; ie < end; ie += 3) {
        // ---- edge ie (buf 0) ----
        if (ie + 2 < end) GATHER(C, eids[ie + 2]);
        FENCE();
        COMPUTE(0);
        if (ie + 1 < end) COMMIT(B, 1);
        // ---- edge ie+1 (buf 1) ----
        if (ie + 1 < end) {
            if (ie + 3 < end) GATHER(A, eids[ie + 3]);
            FENCE();
            COMPUTE(1);
            if (ie + 2 < end) COMMIT(C, 2);
        }
        // ---- edge ie+2 (buf 2) ----
        if (ie + 2 < end) {
            if (ie + 4 < end) GATHER(B, eids[ie + 4]);
            FENCE();
            COMPUTE(2);
            if (ie + 3 < end) COMMIT(A, 0);
        }
    }

    #pragma unroll
    for (int r = 0; r < 25; r++) {
        const int i = 2 * r + h;
        if (i < NCOEF)
            out[(size_t)n * (NCOEF * 32) + i * 32 + c] = acc[r];
    }
}

// ---------------------------------------------------------------------------
extern "C" void kernel_launch(void* const* d_in, const int* in_sizes, int n_in,
                              void* d_out, int out_size, void* d_ws, size_t ws_size,
                              hipStream_t stream)
{
    const int*   an   = (const int*)  d_in[0];
    const int*   ei   = (const int*)  d_in[1];
    const float* ed   = (const float*)d_in[2];
    const float* wig  = (const float*)d_in[3];
    const float* semb = (const float*)d_in[4];
    const float* temb = (const float*)d_in[5];
    const float* W1   = (const float*)d_in[6];
    const float* b1   = (const float*)d_in[7];
    const float* g1   = (const float*)d_in[8];
    const float* be1  = (const float*)d_in[9];
    const float* W2   = (const float*)d_in[10];
    const float* b2   = (const float*)d_in[11];
    const float* g2   = (const float*)d_in[12];
    const float* be2  = (const float*)d_in[13];
    const float* W3   = (const float*)d_in[14];
    const float* b3   = (const float*)d_in[15];
    float* out = (float*)d_out;

    uintptr_t p = (uintptr_t)d_ws;
    #define ALLOC(ptr, type, count) \
        p = (p + 15) & ~(uintptr_t)15; type* ptr = (type*)p; p += sizeof(type) * (count)
    ALLOC(y3,     ushort_t, (size_t)E_EDGES * W3OUT);
    ALLOC(cnt,    int,      N_NODES);
    ALLOC(offs,   int,      N_NODES + 1);
    ALLOC(cursor, int,      N_NODES);
    ALLOC(eids,   int,      E_EDGES);
    ALLOC(sW1,    float,    NELEM * HD);
    ALLOC(tW1,    float,    NELEM * HD);
    ALLOC(W1T,    ushort_t, 64 * 128);
    ALLOC(W2T,    ushort_t, 64 * 64);
    ALLOC(W3T,    ushort_t, 224 * 64);
    #undef ALLOC
    if (p - (uintptr_t)d_ws > ws_size) return;

    k_prep<<<56, 256, 0, stream>>>(semb, temb, W1, W2, W3,
                                   sW1, tW1, W1T, W2T, W3T, cnt);
    k_mlp<<<E_EDGES / 64, 256, 0, stream>>>(an, ei, ed, sW1, tW1,
                                            W1T, W2T, W3T,
                                            b1, g1, be1, b2, g2, be2,
                                            b3, y3, cnt);
    k_scan<<<1, 1024, 0, stream>>>(cnt, offs, cursor);
    k_scatter<<<(E_EDGES + 255) / 256, 256, 0, stream>>>(ei, cursor, eids);
    k_out<<<N_NODES / 4, 256, 0, stream>>>(wig, y3, offs, eids, out);
}